// Round 1
// baseline (667.104 us; speedup 1.0000x reference)
//
#include <hip/hip_runtime.h>
#include <stdint.h>

// ---------------- bf16 helpers (raw ushort storage) ----------------
__device__ __forceinline__ float bflo(unsigned int u) {
    union { unsigned int u; float f; } c; c.u = u << 16; return c.f;
}
__device__ __forceinline__ float bfhi(unsigned int u) {
    union { unsigned int u; float f; } c; c.u = u & 0xffff0000u; return c.f;
}
__device__ __forceinline__ unsigned int f2bf(float f) {
    union { float f; unsigned int u; } c; c.f = f;
    unsigned int u = c.u;
    u += 0x7fffu + ((u >> 16) & 1u);   // round-to-nearest-even
    return u >> 16;
}
__device__ __forceinline__ unsigned int packbf(float a, float b) {
    return f2bf(a) | (f2bf(b) << 16);
}

// ---------------- degree histogram ----------------
__global__ void k_hist(const int* __restrict__ src, const int* __restrict__ dst,
                       int* __restrict__ out_deg, int* __restrict__ in_deg, int E) {
    int stride = gridDim.x * blockDim.x;
    for (int i = blockIdx.x * blockDim.x + threadIdx.x; i < E; i += stride) {
        atomicAdd(&out_deg[src[i]], 1);
        atomicAdd(&in_deg[dst[i]], 1);
    }
}

// ---------------- norms ----------------
__global__ void k_norms(const int* __restrict__ out_deg, const int* __restrict__ in_deg,
                        float* __restrict__ out_norm, float* __restrict__ in_norm, int N) {
    int i = blockIdx.x * blockDim.x + threadIdx.x;
    if (i < N) {
        out_norm[i] = rsqrtf(fmaxf((float)out_deg[i], 1.0f));
        in_norm[i]  = rsqrtf(fmaxf((float)in_deg[i],  1.0f));
    }
}

// ---------------- prefix-sum (3-phase) ----------------
__global__ __launch_bounds__(1024) void k_scan_block(const int* __restrict__ in,
                                                     int* __restrict__ row_ptr, // writes row_ptr[i+1]
                                                     int* __restrict__ partials, int n) {
    __shared__ int sh[1024];
    int i = blockIdx.x * 1024 + threadIdx.x;
    int v = (i < n) ? in[i] : 0;
    sh[threadIdx.x] = v;
    __syncthreads();
    for (int off = 1; off < 1024; off <<= 1) {
        int t = (threadIdx.x >= off) ? sh[threadIdx.x - off] : 0;
        __syncthreads();
        sh[threadIdx.x] += t;
        __syncthreads();
    }
    if (i < n) row_ptr[i + 1] = sh[threadIdx.x];          // inclusive within block
    if (threadIdx.x == 1023) partials[blockIdx.x] = sh[1023];
}

__global__ __launch_bounds__(1024) void k_scan_partials(int* __restrict__ partials, int nb) {
    __shared__ int sh[1024];
    int v = (threadIdx.x < nb) ? partials[threadIdx.x] : 0;
    sh[threadIdx.x] = v;
    __syncthreads();
    for (int off = 1; off < 1024; off <<= 1) {
        int t = (threadIdx.x >= off) ? sh[threadIdx.x - off] : 0;
        __syncthreads();
        sh[threadIdx.x] += t;
        __syncthreads();
    }
    if (threadIdx.x < nb) partials[threadIdx.x] = sh[threadIdx.x] - v; // exclusive
}

__global__ void k_scan_finalize(int* __restrict__ row_ptr, const int* __restrict__ partials,
                                int* __restrict__ cursor, int n) {
    int i = blockIdx.x * blockDim.x + threadIdx.x;
    if (i < n) {
        int v = row_ptr[i + 1] + partials[i >> 10];
        row_ptr[i + 1] = v;
        if (i + 1 < n) cursor[i + 1] = v;
        if (i == 0) { row_ptr[0] = 0; cursor[0] = 0; }
    }
}

// ---------------- edge scatter into CSR buckets ----------------
__global__ void k_scatter(const int* __restrict__ src, const int* __restrict__ dst,
                          int* __restrict__ cursor, int* __restrict__ ssrc, int E) {
    int stride = gridDim.x * blockDim.x;
    for (int i = blockIdx.x * blockDim.x + threadIdx.x; i < E; i += stride) {
        int p = atomicAdd(&cursor[dst[i]], 1);
        ssrc[p] = src[i];
    }
}

// ---------------- GEMM: out[N,128](bf16) = (X * scale[:,None]) @ W[128,128] ----------------
// 64 rows x 128 cols per block of 256 threads. W in LDS as bf16 (32KB),
// X tile in LDS f32 with XOR bank swizzle (32KB). Micro-tile 4 rows x 8 cols.
template <typename TIN>
__global__ __launch_bounds__(256) void gemm128(const TIN* __restrict__ X,
                                               const float* __restrict__ scale,
                                               const float* __restrict__ W,
                                               unsigned short* __restrict__ out, int N) {
    __shared__ __align__(16) float Xs[64 * 128];
    __shared__ __align__(16) unsigned short Ws[128 * 128];
    const int tid = threadIdx.x;

    // stage W (f32 global -> bf16 LDS)
    for (int i = tid; i < (128 * 128) / 4; i += 256) {
        const float4 w = ((const float4*)W)[i];
        int base = i * 4;
        uint2 pp;
        pp.x = packbf(w.x, w.y);
        pp.y = packbf(w.z, w.w);
        *(uint2*)&Ws[base] = pp;
    }

    // stage X tile with scale; column index XOR-swizzled per row group
    const int r0 = blockIdx.x * 64;
    const int k0 = (tid & 31) * 4;
    for (int rr = (tid >> 5); rr < 64; rr += 8) {
        const int r = r0 + rr;
        float v0 = 0.f, v1 = 0.f, v2 = 0.f, v3 = 0.f;
        if (r < N) {
            float sc = scale ? scale[r] : 1.0f;
            if constexpr (sizeof(TIN) == 4) {
                const float4 v = *(const float4*)&X[(size_t)r * 128 + k0];
                v0 = v.x * sc; v1 = v.y * sc; v2 = v.z * sc; v3 = v.w * sc;
            } else {
                const ushort4 v = *(const ushort4*)&X[(size_t)r * 128 + k0];
                v0 = bflo(v.x) * sc; v1 = bflo(v.y) * sc;
                v2 = bflo(v.z) * sc; v3 = bflo(v.w) * sc;
            }
        }
        const int sw = ((rr >> 2) & 3) << 3;
        float* dp = &Xs[rr * 128 + (k0 ^ sw)];
        dp[0] = v0; dp[1] = v1; dp[2] = v2; dp[3] = v3;
    }
    __syncthreads();

    const int jt = (tid & 15) * 8;        // 8 output cols
    const int rt = (tid >> 4) * 4;        // 4 output rows
    const int sw = ((tid >> 4) & 3) << 3; // matches row-group swizzle
    float acc[4][8];
#pragma unroll
    for (int i = 0; i < 4; ++i)
#pragma unroll
        for (int j = 0; j < 8; ++j) acc[i][j] = 0.f;

    for (int k = 0; k < 128; ++k) {
        const int kk = k ^ sw;
        float a0 = Xs[(rt + 0) * 128 + kk];
        float a1 = Xs[(rt + 1) * 128 + kk];
        float a2 = Xs[(rt + 2) * 128 + kk];
        float a3 = Xs[(rt + 3) * 128 + kk];
        const uint4 bw = *(const uint4*)&Ws[k * 128 + jt];
        float b[8];
        b[0] = bflo(bw.x); b[1] = bfhi(bw.x);
        b[2] = bflo(bw.y); b[3] = bfhi(bw.y);
        b[4] = bflo(bw.z); b[5] = bfhi(bw.z);
        b[6] = bflo(bw.w); b[7] = bfhi(bw.w);
#pragma unroll
        for (int j = 0; j < 8; ++j) {
            acc[0][j] = fmaf(a0, b[j], acc[0][j]);
            acc[1][j] = fmaf(a1, b[j], acc[1][j]);
            acc[2][j] = fmaf(a2, b[j], acc[2][j]);
            acc[3][j] = fmaf(a3, b[j], acc[3][j]);
        }
    }

#pragma unroll
    for (int i = 0; i < 4; ++i) {
        const int r = r0 + rt + i;
        if (r < N) {
            uint4 o;
            o.x = packbf(acc[i][0], acc[i][1]);
            o.y = packbf(acc[i][2], acc[i][3]);
            o.z = packbf(acc[i][4], acc[i][5]);
            o.w = packbf(acc[i][6], acc[i][7]);
            *(uint4*)&out[(size_t)r * 128 + jt] = o;
        }
    }
}

// ---------------- CSR aggregation (one wave per dst node) ----------------
// FINAL=0: h = relu(agg*in_norm + bias) -> Hout (bf16)
// FINAL=1: v = agg*in_norm + bias + Res; out[d,:] = v @ mlpW + mlpB (f32)
template <int FINAL>
__global__ __launch_bounds__(256) void spmm_agg(const unsigned short* __restrict__ T,
                                                const int* __restrict__ row_ptr,
                                                const int* __restrict__ ssrc,
                                                const float* __restrict__ in_norm,
                                                const float* __restrict__ bias,
                                                unsigned short* __restrict__ Hout,
                                                const unsigned short* __restrict__ Res,
                                                const float* __restrict__ mlpW,
                                                const float* __restrict__ mlpB,
                                                float* __restrict__ out, int N) {
    const int lane = threadIdx.x & 63;
    const int d = blockIdx.x * 4 + (threadIdx.x >> 6);
    if (d >= N) return;

    const int start = row_ptr[d], end = row_ptr[d + 1];
    float ax = 0.f, ay = 0.f;
    const unsigned int* T32 = (const unsigned int*)T;

    for (int base = start; base < end; base += 64) {
        const int cnt = min(64, end - base);
        int sl = (lane < cnt) ? ssrc[base + lane] : 0;
        int i = 0;
        for (; i + 4 <= cnt; i += 4) {
            int s0 = __shfl(sl, i + 0);
            int s1 = __shfl(sl, i + 1);
            int s2 = __shfl(sl, i + 2);
            int s3 = __shfl(sl, i + 3);
            unsigned int w0 = T32[(size_t)s0 * 64 + lane];
            unsigned int w1 = T32[(size_t)s1 * 64 + lane];
            unsigned int w2 = T32[(size_t)s2 * 64 + lane];
            unsigned int w3 = T32[(size_t)s3 * 64 + lane];
            ax += bflo(w0) + bflo(w1) + bflo(w2) + bflo(w3);
            ay += bfhi(w0) + bfhi(w1) + bfhi(w2) + bfhi(w3);
        }
        for (; i < cnt; ++i) {
            int s = __shfl(sl, i);
            unsigned int w = T32[(size_t)s * 64 + lane];
            ax += bflo(w);
            ay += bfhi(w);
        }
    }

    const float inr = in_norm[d];
    const float2 bb = ((const float2*)bias)[lane];
    float vx = ax * inr + bb.x;
    float vy = ay * inr + bb.y;

    if constexpr (FINAL == 0) {
        vx = fmaxf(vx, 0.f);
        vy = fmaxf(vy, 0.f);
        ((unsigned int*)Hout)[(size_t)d * 64 + lane] = packbf(vx, vy);
    } else {
        unsigned int rw = ((const unsigned int*)Res)[(size_t)d * 64 + lane];
        vx += bflo(rw);
        vy += bfhi(rw);
        // mlpW rows 2*lane, 2*lane+1 -> float4 {w(2l,0), w(2l,1), w(2l+1,0), w(2l+1,1)}
        const float4 mw = ((const float4*)mlpW)[lane];
        float p0 = vx * mw.x + vy * mw.z;
        float p1 = vx * mw.y + vy * mw.w;
#pragma unroll
        for (int off = 32; off > 0; off >>= 1) {
            p0 += __shfl_xor(p0, off);
            p1 += __shfl_xor(p1, off);
        }
        if (lane == 0) {
            out[(size_t)d * 2 + 0] = p0 + mlpB[0];
            out[(size_t)d * 2 + 1] = p1 + mlpB[1];
        }
    }
}

// ---------------- launch ----------------
extern "C" void kernel_launch(void* const* d_in, const int* in_sizes, int n_in,
                              void* d_out, int out_size, void* d_ws, size_t ws_size,
                              hipStream_t stream) {
    const float* x     = (const float*)d_in[0];
    const int*   src   = (const int*)d_in[1];
    const int*   dst   = (const int*)d_in[2];
    const float* W1    = (const float*)d_in[3];
    const float* b1    = (const float*)d_in[4];
    const float* W2    = (const float*)d_in[5];
    const float* b2    = (const float*)d_in[6];
    const float* res_W = (const float*)d_in[7];
    const float* mlp_W = (const float*)d_in[8];
    const float* mlp_b = (const float*)d_in[9];
    float* out = (float*)d_out;

    const int N = in_sizes[0] / 128;
    const int E = in_sizes[1];

    // workspace layout
    char* p = (char*)d_ws;
    unsigned short* A = (unsigned short*)p;  p += (size_t)N * 128 * 2;   // transformed feats
    unsigned short* B = (unsigned short*)p;  p += (size_t)N * 128 * 2;   // h1 / res
    float* out_norm = (float*)p;             p += (size_t)N * 4;
    float* in_norm  = (float*)p;             p += (size_t)N * 4;
    int* out_deg    = (int*)p;               p += (size_t)N * 4;
    int* in_deg     = (int*)p;               p += (size_t)N * 4;
    int* row_ptr    = (int*)p;               p += (size_t)(N + 1) * 4;
    int* cursor     = (int*)p;               p += (size_t)N * 4;
    int* partials   = (int*)p;               p += (size_t)1024 * 4;
    int* ssrc       = (int*)p;               p += (size_t)E * 4;

    const int gE = (E + 255) / 256;
    const int gN = (N + 255) / 256;
    const int nb = (N + 1023) / 1024;
    const int gGemm = (N + 63) / 64;
    const int gSpmm = (N + 3) / 4;

    // 1. degrees + norms
    hipMemsetAsync(out_deg, 0, (size_t)2 * N * 4, stream);   // out_deg and in_deg adjacent
    k_hist<<<gE, 256, 0, stream>>>(src, dst, out_deg, in_deg, E);
    k_norms<<<gN, 256, 0, stream>>>(out_deg, in_deg, out_norm, in_norm, N);

    // 2. CSR build (by dst)
    k_scan_block<<<nb, 1024, 0, stream>>>(in_deg, row_ptr, partials, N);
    k_scan_partials<<<1, 1024, 0, stream>>>(partials, nb);
    k_scan_finalize<<<gN, 256, 0, stream>>>(row_ptr, partials, cursor, N);
    k_scatter<<<gE, 256, 0, stream>>>(src, dst, cursor, ssrc, E);

    // 3. layer 1: t1 = (x * out_norm) @ W1 -> A ; h1 = relu(agg*in_norm + b1) -> B
    gemm128<float><<<gGemm, 256, 0, stream>>>(x, out_norm, W1, A, N);
    spmm_agg<0><<<gSpmm, 256, 0, stream>>>(A, row_ptr, ssrc, in_norm, b1, B,
                                           (const unsigned short*)nullptr, nullptr, nullptr,
                                           nullptr, N);

    // 4. layer 2: t2 = (h1 * out_norm) @ W2 -> A ; res = x @ res_W -> B
    gemm128<unsigned short><<<gGemm, 256, 0, stream>>>(B, out_norm, W2, A, N);
    gemm128<float><<<gGemm, 256, 0, stream>>>(x, (const float*)nullptr, res_W, B, N);

    // 5. final aggregation + residual + MLP head -> out
    spmm_agg<1><<<gSpmm, 256, 0, stream>>>(A, row_ptr, ssrc, in_norm, b2, nullptr,
                                           B, mlp_W, mlp_b, out, N);

    (void)n_in; (void)out_size; (void)ws_size;
}

// Round 2
// 606.799 us; speedup vs baseline: 1.0994x; 1.0994x over previous
//
#include <hip/hip_runtime.h>
#include <stdint.h>

// ---------------- bf16 helpers (raw ushort storage) ----------------
__device__ __forceinline__ float bflo(unsigned int u) {
    union { unsigned int u; float f; } c; c.u = u << 16; return c.f;
}
__device__ __forceinline__ float bfhi(unsigned int u) {
    union { unsigned int u; float f; } c; c.u = u & 0xffff0000u; return c.f;
}
__device__ __forceinline__ unsigned int f2bf(float f) {
    union { float f; unsigned int u; } c; c.f = f;
    unsigned int u = c.u;
    u += 0x7fffu + ((u >> 16) & 1u);   // round-to-nearest-even
    return u >> 16;
}
__device__ __forceinline__ unsigned int packbf(float a, float b) {
    return f2bf(a) | (f2bf(b) << 16);
}

// ---------------- counting-sort parameters ----------------
#define RANGE_BITS 15
#define RANGE (1 << RANGE_BITS)     // 32768 nodes per LDS range (64 KB @ 2B/node)
#define NSLICE 32                   // edge slices

// ---------------- LDS-privatized degree histogram (no global atomics) ----------------
// grid (NR, NSLICE, 2): z=0 -> src array (out-degree), z=1 -> dst array (in-degree)
// Partial counts are 16-bit, packed 2 nodes per uint. Per-slice count <= 50000 < 2^16.
__global__ __launch_bounds__(256) void k_hist_lds(const int* __restrict__ src,
                                                  const int* __restrict__ dst,
                                                  unsigned int* __restrict__ partialS,
                                                  unsigned int* __restrict__ partialD,
                                                  int E, int EPS) {
    __shared__ unsigned int cnt[RANGE / 2];   // 64 KB
    const int r = blockIdx.x;
    const int s = blockIdx.y;
    const int a = blockIdx.z;
    const int* __restrict__ arr = a ? dst : src;
    unsigned int* part = (a ? partialD : partialS)
                         + ((size_t)r * NSLICE + s) * (RANGE / 2);
    for (int i = threadIdx.x; i < RANGE / 2; i += 256) cnt[i] = 0;
    __syncthreads();
    const int e0 = s * EPS;
    const int e1 = min(E, e0 + EPS);
    for (int e = e0 + threadIdx.x; e < e1; e += 256) {
        const int idx = arr[e];
        if ((idx >> RANGE_BITS) == r) {
            const int local = idx & (RANGE - 1);
            atomicAdd(&cnt[local >> 1], 1u << ((local & 1) << 4));
        }
    }
    __syncthreads();
    for (int i = threadIdx.x; i < RANGE / 2; i += 256) part[i] = cnt[i];
}

// ---------------- reduce partials -> degrees/norms; dst partials -> slice prefixes ----------------
// grid (NR*RANGE/2/256, 2). Unpacks 16-bit halves to avoid carry across halves.
__global__ __launch_bounds__(256) void k_deg_reduce(unsigned int* __restrict__ pS,
                                                    unsigned int* __restrict__ pD,
                                                    float* __restrict__ out_norm,
                                                    float* __restrict__ in_norm,
                                                    int* __restrict__ in_deg, int N) {
    const int a = blockIdx.y;
    const int t = blockIdx.x * 256 + threadIdx.x;   // 0 .. NR*RANGE/2-1
    const int r = t / (RANGE / 2);
    const int w = t - r * (RANGE / 2);
    unsigned int* base = (a ? pD : pS) + (size_t)r * NSLICE * (RANGE / 2) + w;
    unsigned int lo = 0, hi = 0;
    if (a) {
        // in-place exclusive prefix over slices (packed), accumulate totals
        for (int s = 0; s < NSLICE; ++s) {
            const unsigned int v = base[(size_t)s * (RANGE / 2)];
            base[(size_t)s * (RANGE / 2)] = lo | (hi << 16);
            lo += v & 0xffffu; hi += v >> 16;
        }
    } else {
        for (int s = 0; s < NSLICE; ++s) {
            const unsigned int v = base[(size_t)s * (RANGE / 2)];
            lo += v & 0xffffu; hi += v >> 16;
        }
    }
    const int n0 = r * RANGE + 2 * w, n1 = n0 + 1;
    if (a) {
        if (n0 < N) { in_deg[n0] = (int)lo; in_norm[n0] = rsqrtf(fmaxf((float)lo, 1.f)); }
        if (n1 < N) { in_deg[n1] = (int)hi; in_norm[n1] = rsqrtf(fmaxf((float)hi, 1.f)); }
    } else {
        if (n0 < N) out_norm[n0] = rsqrtf(fmaxf((float)lo, 1.f));
        if (n1 < N) out_norm[n1] = rsqrtf(fmaxf((float)hi, 1.f));
    }
}

// ---------------- prefix-sum (3-phase) ----------------
__global__ __launch_bounds__(1024) void k_scan_block(const int* __restrict__ in,
                                                     int* __restrict__ row_ptr, // writes row_ptr[i+1]
                                                     int* __restrict__ partials, int n) {
    __shared__ int sh[1024];
    int i = blockIdx.x * 1024 + threadIdx.x;
    int v = (i < n) ? in[i] : 0;
    sh[threadIdx.x] = v;
    __syncthreads();
    for (int off = 1; off < 1024; off <<= 1) {
        int t = (threadIdx.x >= off) ? sh[threadIdx.x - off] : 0;
        __syncthreads();
        sh[threadIdx.x] += t;
        __syncthreads();
    }
    if (i < n) row_ptr[i + 1] = sh[threadIdx.x];          // inclusive within block
    if (threadIdx.x == 1023) partials[blockIdx.x] = sh[1023];
}

__global__ __launch_bounds__(1024) void k_scan_partials(int* __restrict__ partials, int nb) {
    __shared__ int sh[1024];
    int v = (threadIdx.x < nb) ? partials[threadIdx.x] : 0;
    sh[threadIdx.x] = v;
    __syncthreads();
    for (int off = 1; off < 1024; off <<= 1) {
        int t = (threadIdx.x >= off) ? sh[threadIdx.x - off] : 0;
        __syncthreads();
        sh[threadIdx.x] += t;
        __syncthreads();
    }
    if (threadIdx.x < nb) partials[threadIdx.x] = sh[threadIdx.x] - v; // exclusive
}

__global__ void k_scan_finalize(int* __restrict__ row_ptr, const int* __restrict__ partials,
                                int n) {
    int i = blockIdx.x * blockDim.x + threadIdx.x;
    if (i < n) {
        row_ptr[i + 1] += partials[i >> 10];
        if (i == 0) row_ptr[0] = 0;
    }
}

// ---------------- deterministic CSR scatter (no global atomics) ----------------
// grid (NR, NSLICE). LDS cursor starts at the per-(range,slice) exclusive prefix;
// pos = row_ptr[d] + (cursor[d]++). prefix+rank <= total degree << 2^16.
__global__ __launch_bounds__(256) void k_scatter_lds(const int* __restrict__ src,
                                                     const int* __restrict__ dst,
                                                     const unsigned int* __restrict__ pD,
                                                     const int* __restrict__ row_ptr,
                                                     int* __restrict__ ssrc, int E, int EPS) {
    __shared__ unsigned int cur[RANGE / 2];   // 64 KB
    const int r = blockIdx.x;
    const int s = blockIdx.y;
    const unsigned int* pre = pD + ((size_t)r * NSLICE + s) * (RANGE / 2);
    for (int i = threadIdx.x; i < RANGE / 2; i += 256) cur[i] = pre[i];
    __syncthreads();
    const int e0 = s * EPS;
    const int e1 = min(E, e0 + EPS);
    for (int e = e0 + threadIdx.x; e < e1; e += 256) {
        const int d = dst[e];
        if ((d >> RANGE_BITS) == r) {
            const int local = d & (RANGE - 1);
            const int sh = (local & 1) << 4;
            const unsigned int old = atomicAdd(&cur[local >> 1], 1u << sh);
            const unsigned int off = (old >> sh) & 0xffffu;
            ssrc[row_ptr[d] + (int)off] = src[e];
        }
    }
}

// ---------------- GEMM: out[N,128](bf16) = (X * scale[:,None]) @ W[128,128] ----------------
template <typename TIN>
__global__ __launch_bounds__(256) void gemm128(const TIN* __restrict__ X,
                                               const float* __restrict__ scale,
                                               const float* __restrict__ W,
                                               unsigned short* __restrict__ out, int N) {
    __shared__ __align__(16) float Xs[64 * 128];
    __shared__ __align__(16) unsigned short Ws[128 * 128];
    const int tid = threadIdx.x;

    for (int i = tid; i < (128 * 128) / 4; i += 256) {
        const float4 w = ((const float4*)W)[i];
        int base = i * 4;
        uint2 pp;
        pp.x = packbf(w.x, w.y);
        pp.y = packbf(w.z, w.w);
        *(uint2*)&Ws[base] = pp;
    }

    const int r0 = blockIdx.x * 64;
    const int k0 = (tid & 31) * 4;
    for (int rr = (tid >> 5); rr < 64; rr += 8) {
        const int r = r0 + rr;
        float v0 = 0.f, v1 = 0.f, v2 = 0.f, v3 = 0.f;
        if (r < N) {
            float sc = scale ? scale[r] : 1.0f;
            if constexpr (sizeof(TIN) == 4) {
                const float4 v = *(const float4*)&X[(size_t)r * 128 + k0];
                v0 = v.x * sc; v1 = v.y * sc; v2 = v.z * sc; v3 = v.w * sc;
            } else {
                const ushort4 v = *(const ushort4*)&X[(size_t)r * 128 + k0];
                v0 = bflo(v.x) * sc; v1 = bflo(v.y) * sc;
                v2 = bflo(v.z) * sc; v3 = bflo(v.w) * sc;
            }
        }
        const int sw = ((rr >> 2) & 3) << 3;
        float* dp = &Xs[rr * 128 + (k0 ^ sw)];
        dp[0] = v0; dp[1] = v1; dp[2] = v2; dp[3] = v3;
    }
    __syncthreads();

    const int jt = (tid & 15) * 8;
    const int rt = (tid >> 4) * 4;
    const int sw = ((tid >> 4) & 3) << 3;
    float acc[4][8];
#pragma unroll
    for (int i = 0; i < 4; ++i)
#pragma unroll
        for (int j = 0; j < 8; ++j) acc[i][j] = 0.f;

    for (int k = 0; k < 128; ++k) {
        const int kk = k ^ sw;
        float a0 = Xs[(rt + 0) * 128 + kk];
        float a1 = Xs[(rt + 1) * 128 + kk];
        float a2 = Xs[(rt + 2) * 128 + kk];
        float a3 = Xs[(rt + 3) * 128 + kk];
        const uint4 bw = *(const uint4*)&Ws[k * 128 + jt];
        float b[8];
        b[0] = bflo(bw.x); b[1] = bfhi(bw.x);
        b[2] = bflo(bw.y); b[3] = bfhi(bw.y);
        b[4] = bflo(bw.z); b[5] = bfhi(bw.z);
        b[6] = bflo(bw.w); b[7] = bfhi(bw.w);
#pragma unroll
        for (int j = 0; j < 8; ++j) {
            acc[0][j] = fmaf(a0, b[j], acc[0][j]);
            acc[1][j] = fmaf(a1, b[j], acc[1][j]);
            acc[2][j] = fmaf(a2, b[j], acc[2][j]);
            acc[3][j] = fmaf(a3, b[j], acc[3][j]);
        }
    }

#pragma unroll
    for (int i = 0; i < 4; ++i) {
        const int r = r0 + rt + i;
        if (r < N) {
            uint4 o;
            o.x = packbf(acc[i][0], acc[i][1]);
            o.y = packbf(acc[i][2], acc[i][3]);
            o.z = packbf(acc[i][4], acc[i][5]);
            o.w = packbf(acc[i][6], acc[i][7]);
            *(uint4*)&out[(size_t)r * 128 + jt] = o;
        }
    }
}

// ---------------- CSR aggregation (one wave per dst node) ----------------
template <int FINAL>
__global__ __launch_bounds__(256) void spmm_agg(const unsigned short* __restrict__ T,
                                                const int* __restrict__ row_ptr,
                                                const int* __restrict__ ssrc,
                                                const float* __restrict__ in_norm,
                                                const float* __restrict__ bias,
                                                unsigned short* __restrict__ Hout,
                                                const unsigned short* __restrict__ Res,
                                                const float* __restrict__ mlpW,
                                                const float* __restrict__ mlpB,
                                                float* __restrict__ out, int N) {
    const int lane = threadIdx.x & 63;
    const int d = blockIdx.x * 4 + (threadIdx.x >> 6);
    if (d >= N) return;

    const int start = row_ptr[d], end = row_ptr[d + 1];
    float ax = 0.f, ay = 0.f;
    const unsigned int* T32 = (const unsigned int*)T;

    for (int base = start; base < end; base += 64) {
        const int cnt = min(64, end - base);
        int sl = (lane < cnt) ? ssrc[base + lane] : 0;
        int i = 0;
        for (; i + 4 <= cnt; i += 4) {
            int s0 = __shfl(sl, i + 0);
            int s1 = __shfl(sl, i + 1);
            int s2 = __shfl(sl, i + 2);
            int s3 = __shfl(sl, i + 3);
            unsigned int w0 = T32[(size_t)s0 * 64 + lane];
            unsigned int w1 = T32[(size_t)s1 * 64 + lane];
            unsigned int w2 = T32[(size_t)s2 * 64 + lane];
            unsigned int w3 = T32[(size_t)s3 * 64 + lane];
            ax += bflo(w0) + bflo(w1) + bflo(w2) + bflo(w3);
            ay += bfhi(w0) + bfhi(w1) + bfhi(w2) + bfhi(w3);
        }
        for (; i < cnt; ++i) {
            int s = __shfl(sl, i);
            unsigned int w = T32[(size_t)s * 64 + lane];
            ax += bflo(w);
            ay += bfhi(w);
        }
    }

    const float inr = in_norm[d];
    const float2 bb = ((const float2*)bias)[lane];
    float vx = ax * inr + bb.x;
    float vy = ay * inr + bb.y;

    if constexpr (FINAL == 0) {
        vx = fmaxf(vx, 0.f);
        vy = fmaxf(vy, 0.f);
        ((unsigned int*)Hout)[(size_t)d * 64 + lane] = packbf(vx, vy);
    } else {
        unsigned int rw = ((const unsigned int*)Res)[(size_t)d * 64 + lane];
        vx += bflo(rw);
        vy += bfhi(rw);
        const float4 mw = ((const float4*)mlpW)[lane];
        float p0 = vx * mw.x + vy * mw.z;
        float p1 = vx * mw.y + vy * mw.w;
#pragma unroll
        for (int off = 32; off > 0; off >>= 1) {
            p0 += __shfl_xor(p0, off);
            p1 += __shfl_xor(p1, off);
        }
        if (lane == 0) {
            out[(size_t)d * 2 + 0] = p0 + mlpB[0];
            out[(size_t)d * 2 + 1] = p1 + mlpB[1];
        }
    }
}

// ---------------- launch ----------------
extern "C" void kernel_launch(void* const* d_in, const int* in_sizes, int n_in,
                              void* d_out, int out_size, void* d_ws, size_t ws_size,
                              hipStream_t stream) {
    const float* x     = (const float*)d_in[0];
    const int*   src   = (const int*)d_in[1];
    const int*   dst   = (const int*)d_in[2];
    const float* W1    = (const float*)d_in[3];
    const float* b1    = (const float*)d_in[4];
    const float* W2    = (const float*)d_in[5];
    const float* b2    = (const float*)d_in[6];
    const float* res_W = (const float*)d_in[7];
    const float* mlp_W = (const float*)d_in[8];
    const float* mlp_b = (const float*)d_in[9];
    float* out = (float*)d_out;

    const int N = in_sizes[0] / 128;
    const int E = in_sizes[1];
    const int NR = (N + RANGE - 1) >> RANGE_BITS;
    const int EPS = (E + NSLICE - 1) / NSLICE;

    // workspace layout (16B-aligned chunks first)
    char* p = (char*)d_ws;
    unsigned short* A = (unsigned short*)p;  p += (size_t)N * 128 * 2;             // transformed feats
    unsigned short* B = (unsigned short*)p;  p += (size_t)N * 128 * 2;             // h1 / res
    unsigned int* partialS = (unsigned int*)p; p += (size_t)NR * NSLICE * (RANGE / 2) * 4;
    unsigned int* partialD = (unsigned int*)p; p += (size_t)NR * NSLICE * (RANGE / 2) * 4;
    float* out_norm = (float*)p;             p += (size_t)N * 4;
    float* in_norm  = (float*)p;             p += (size_t)N * 4;
    int* in_deg     = (int*)p;               p += (size_t)N * 4;
    int* row_ptr    = (int*)p;               p += (size_t)(N + 1) * 4;
    int* scanpart   = (int*)p;               p += (size_t)1024 * 4;
    int* ssrc       = (int*)p;               p += (size_t)E * 4;

    const int gN = (N + 255) / 256;
    const int nb = (N + 1023) / 1024;
    const int gGemm = (N + 63) / 64;
    const int gSpmm = (N + 3) / 4;

    // 1. degrees + norms + slice prefixes (no global atomics)
    k_hist_lds<<<dim3(NR, NSLICE, 2), 256, 0, stream>>>(src, dst, partialS, partialD, E, EPS);
    k_deg_reduce<<<dim3(NR * (RANGE / 2) / 256, 2), 256, 0, stream>>>(partialS, partialD,
                                                                      out_norm, in_norm, in_deg, N);

    // 2. row_ptr scan + deterministic CSR scatter
    k_scan_block<<<nb, 1024, 0, stream>>>(in_deg, row_ptr, scanpart, N);
    k_scan_partials<<<1, 1024, 0, stream>>>(scanpart, nb);
    k_scan_finalize<<<gN, 256, 0, stream>>>(row_ptr, scanpart, N);
    k_scatter_lds<<<dim3(NR, NSLICE), 256, 0, stream>>>(src, dst, partialD, row_ptr, ssrc, E, EPS);

    // 3. layer 1: t1 = (x * out_norm) @ W1 -> A ; h1 = relu(agg*in_norm + b1) -> B
    gemm128<float><<<gGemm, 256, 0, stream>>>(x, out_norm, W1, A, N);
    spmm_agg<0><<<gSpmm, 256, 0, stream>>>(A, row_ptr, ssrc, in_norm, b1, B,
                                           (const unsigned short*)nullptr, nullptr, nullptr,
                                           nullptr, N);

    // 4. layer 2: t2 = (h1 * out_norm) @ W2 -> A ; res = x @ res_W -> B
    gemm128<unsigned short><<<gGemm, 256, 0, stream>>>(B, out_norm, W2, A, N);
    gemm128<float><<<gGemm, 256, 0, stream>>>(x, (const float*)nullptr, res_W, B, N);

    // 5. final aggregation + residual + MLP head -> out
    spmm_agg<1><<<gSpmm, 256, 0, stream>>>(A, row_ptr, ssrc, in_norm, b2, nullptr,
                                           B, mlp_W, mlp_b, out, N);

    (void)n_in; (void)out_size; (void)ws_size;
}

// Round 3
// 499.387 us; speedup vs baseline: 1.3358x; 1.2151x over previous
//
#include <hip/hip_runtime.h>
#include <stdint.h>

// ---------------- bf16 helpers (raw ushort storage) ----------------
__device__ __forceinline__ float bflo(unsigned int u) {
    union { unsigned int u; float f; } c; c.u = u << 16; return c.f;
}
__device__ __forceinline__ float bfhi(unsigned int u) {
    union { unsigned int u; float f; } c; c.u = u & 0xffff0000u; return c.f;
}
__device__ __forceinline__ unsigned int f2bf(float f) {
    union { float f; unsigned int u; } c; c.f = f;
    unsigned int u = c.u;
    u += 0x7fffu + ((u >> 16) & 1u);   // round-to-nearest-even
    return u >> 16;
}
__device__ __forceinline__ unsigned int packbf(float a, float b) {
    return f2bf(a) | (f2bf(b) << 16);
}

// ---------------- counting-sort parameters ----------------
#define RANGE_BITS 14
#define RANGE (1 << RANGE_BITS)     // 16384 nodes per LDS range (32 KB @ 2B/node)
#define NR_PAD 8                    // ranges padded to 8 for XCD swizzle (range = bid & 7)
#define NSLICE 64                   // edge slices; per-slice count <= E/64 = 25000 < 2^16

// ---------------- LDS-privatized degree histogram (no global atomics) ----------------
// grid (NR_PAD*NSLICE, 2): y=0 -> src array (out-degree), y=1 -> dst array (in-degree)
// Block x: range = x & 7 (XCD-locality swizzle), slice = x >> 3.
__global__ __launch_bounds__(256) void k_hist_lds(const int* __restrict__ src,
                                                  const int* __restrict__ dst,
                                                  unsigned int* __restrict__ partialS,
                                                  unsigned int* __restrict__ partialD,
                                                  int E, int EPS) {
    __shared__ unsigned int cnt[RANGE / 2];   // 32 KB
    const int r = blockIdx.x & 7;
    const int s = blockIdx.x >> 3;
    const int a = blockIdx.y;
    const int* __restrict__ arr = a ? dst : src;
    unsigned int* part = (a ? partialD : partialS)
                         + ((size_t)r * NSLICE + s) * (RANGE / 2);
    for (int i = threadIdx.x; i < RANGE / 2; i += 256) cnt[i] = 0;
    __syncthreads();
    const int e0 = s * EPS;
    const int e1 = min(E, e0 + EPS);
    int e = e0 + threadIdx.x * 4;
    for (; e + 3 < e1; e += 1024) {
        const int4 v = *(const int4*)&arr[e];
        if ((v.x >> RANGE_BITS) == r) { int l = v.x & (RANGE - 1); atomicAdd(&cnt[l >> 1], 1u << ((l & 1) << 4)); }
        if ((v.y >> RANGE_BITS) == r) { int l = v.y & (RANGE - 1); atomicAdd(&cnt[l >> 1], 1u << ((l & 1) << 4)); }
        if ((v.z >> RANGE_BITS) == r) { int l = v.z & (RANGE - 1); atomicAdd(&cnt[l >> 1], 1u << ((l & 1) << 4)); }
        if ((v.w >> RANGE_BITS) == r) { int l = v.w & (RANGE - 1); atomicAdd(&cnt[l >> 1], 1u << ((l & 1) << 4)); }
    }
    for (; e < e1; ++e) {
        const int idx = arr[e];
        if ((idx >> RANGE_BITS) == r) { int l = idx & (RANGE - 1); atomicAdd(&cnt[l >> 1], 1u << ((l & 1) << 4)); }
    }
    __syncthreads();
    for (int i = threadIdx.x; i < RANGE / 2; i += 256) part[i] = cnt[i];
}

// ---------------- reduce partials -> degrees/norms; dst partials -> slice prefixes ----------------
// grid (NR_PAD*RANGE/2/256, 2). Unpacks 16-bit halves to avoid carry across halves.
__global__ __launch_bounds__(256) void k_deg_reduce(unsigned int* __restrict__ pS,
                                                    unsigned int* __restrict__ pD,
                                                    float* __restrict__ out_norm,
                                                    float* __restrict__ in_norm,
                                                    int* __restrict__ in_deg, int N) {
    const int a = blockIdx.y;
    const int t = blockIdx.x * 256 + threadIdx.x;   // 0 .. NR_PAD*RANGE/2-1
    const int r = t >> (RANGE_BITS - 1);
    const int w = t & ((RANGE / 2) - 1);
    unsigned int* base = (a ? pD : pS) + (size_t)r * NSLICE * (RANGE / 2) + w;
    unsigned int lo = 0, hi = 0;
    if (a) {
        // in-place exclusive prefix over slices (packed), accumulate totals
        for (int s = 0; s < NSLICE; ++s) {
            const unsigned int v = base[(size_t)s * (RANGE / 2)];
            base[(size_t)s * (RANGE / 2)] = lo | (hi << 16);
            lo += v & 0xffffu; hi += v >> 16;
        }
    } else {
        for (int s = 0; s < NSLICE; ++s) {
            const unsigned int v = base[(size_t)s * (RANGE / 2)];
            lo += v & 0xffffu; hi += v >> 16;
        }
    }
    const int n0 = r * RANGE + 2 * w, n1 = n0 + 1;
    if (a) {
        if (n0 < N) { in_deg[n0] = (int)lo; in_norm[n0] = rsqrtf(fmaxf((float)lo, 1.f)); }
        if (n1 < N) { in_deg[n1] = (int)hi; in_norm[n1] = rsqrtf(fmaxf((float)hi, 1.f)); }
    } else {
        if (n0 < N) out_norm[n0] = rsqrtf(fmaxf((float)lo, 1.f));
        if (n1 < N) out_norm[n1] = rsqrtf(fmaxf((float)hi, 1.f));
    }
}

// ---------------- prefix-sum (3-phase) ----------------
__global__ __launch_bounds__(1024) void k_scan_block(const int* __restrict__ in,
                                                     int* __restrict__ row_ptr, // writes row_ptr[i+1]
                                                     int* __restrict__ partials, int n) {
    __shared__ int sh[1024];
    int i = blockIdx.x * 1024 + threadIdx.x;
    int v = (i < n) ? in[i] : 0;
    sh[threadIdx.x] = v;
    __syncthreads();
    for (int off = 1; off < 1024; off <<= 1) {
        int t = (threadIdx.x >= off) ? sh[threadIdx.x - off] : 0;
        __syncthreads();
        sh[threadIdx.x] += t;
        __syncthreads();
    }
    if (i < n) row_ptr[i + 1] = sh[threadIdx.x];          // inclusive within block
    if (threadIdx.x == 1023) partials[blockIdx.x] = sh[1023];
}

__global__ __launch_bounds__(1024) void k_scan_partials(int* __restrict__ partials, int nb) {
    __shared__ int sh[1024];
    int v = (threadIdx.x < nb) ? partials[threadIdx.x] : 0;
    sh[threadIdx.x] = v;
    __syncthreads();
    for (int off = 1; off < 1024; off <<= 1) {
        int t = (threadIdx.x >= off) ? sh[threadIdx.x - off] : 0;
        __syncthreads();
        sh[threadIdx.x] += t;
        __syncthreads();
    }
    if (threadIdx.x < nb) partials[threadIdx.x] = sh[threadIdx.x] - v; // exclusive
}

__global__ void k_scan_finalize(int* __restrict__ row_ptr, const int* __restrict__ partials,
                                int n) {
    int i = blockIdx.x * blockDim.x + threadIdx.x;
    if (i < n) {
        row_ptr[i + 1] += partials[i >> 10];
        if (i == 0) row_ptr[0] = 0;
    }
}

// ---------------- deterministic CSR scatter (no global atomics) ----------------
// grid NR_PAD*NSLICE; range = bid & 7 (XCD swizzle), slice = bid >> 3.
// LDS cursor starts at the per-(range,slice) exclusive prefix;
// pos = row_ptr[d] + (cursor[d]++). prefix+rank <= total degree << 2^16.
__global__ __launch_bounds__(256) void k_scatter_lds(const int* __restrict__ src,
                                                     const int* __restrict__ dst,
                                                     const unsigned int* __restrict__ pD,
                                                     const int* __restrict__ row_ptr,
                                                     int* __restrict__ ssrc, int E, int EPS) {
    __shared__ unsigned int cur[RANGE / 2];   // 32 KB
    const int r = blockIdx.x & 7;
    const int s = blockIdx.x >> 3;
    const unsigned int* pre = pD + ((size_t)r * NSLICE + s) * (RANGE / 2);
    for (int i = threadIdx.x; i < RANGE / 2; i += 256) cur[i] = pre[i];
    __syncthreads();
    const int e0 = s * EPS;
    const int e1 = min(E, e0 + EPS);
    int e = e0 + threadIdx.x * 4;
    for (; e + 3 < e1; e += 1024) {
        const int4 v = *(const int4*)&dst[e];
#pragma unroll
        for (int j = 0; j < 4; ++j) {
            const int d = (&v.x)[j];
            if ((d >> RANGE_BITS) == r) {
                const int local = d & (RANGE - 1);
                const int sh = (local & 1) << 4;
                const unsigned int old = atomicAdd(&cur[local >> 1], 1u << sh);
                const unsigned int off = (old >> sh) & 0xffffu;
                ssrc[row_ptr[d] + (int)off] = src[e + j];
            }
        }
    }
    for (; e < e1; ++e) {
        const int d = dst[e];
        if ((d >> RANGE_BITS) == r) {
            const int local = d & (RANGE - 1);
            const int sh = (local & 1) << 4;
            const unsigned int old = atomicAdd(&cur[local >> 1], 1u << sh);
            const unsigned int off = (old >> sh) & 0xffffu;
            ssrc[row_ptr[d] + (int)off] = src[e];
        }
    }
}

// ---------------- GEMM: out[N,128](bf16) = (X * scale[:,None]) @ W[128,128] ----------------
template <typename TIN>
__global__ __launch_bounds__(256) void gemm128(const TIN* __restrict__ X,
                                               const float* __restrict__ scale,
                                               const float* __restrict__ W,
                                               unsigned short* __restrict__ out, int N) {
    __shared__ __align__(16) float Xs[64 * 128];
    __shared__ __align__(16) unsigned short Ws[128 * 128];
    const int tid = threadIdx.x;

    for (int i = tid; i < (128 * 128) / 4; i += 256) {
        const float4 w = ((const float4*)W)[i];
        int base = i * 4;
        uint2 pp;
        pp.x = packbf(w.x, w.y);
        pp.y = packbf(w.z, w.w);
        *(uint2*)&Ws[base] = pp;
    }

    const int r0 = blockIdx.x * 64;
    const int k0 = (tid & 31) * 4;
    for (int rr = (tid >> 5); rr < 64; rr += 8) {
        const int r = r0 + rr;
        float v0 = 0.f, v1 = 0.f, v2 = 0.f, v3 = 0.f;
        if (r < N) {
            float sc = scale ? scale[r] : 1.0f;
            if constexpr (sizeof(TIN) == 4) {
                const float4 v = *(const float4*)&X[(size_t)r * 128 + k0];
                v0 = v.x * sc; v1 = v.y * sc; v2 = v.z * sc; v3 = v.w * sc;
            } else {
                const ushort4 v = *(const ushort4*)&X[(size_t)r * 128 + k0];
                v0 = bflo(v.x) * sc; v1 = bflo(v.y) * sc;
                v2 = bflo(v.z) * sc; v3 = bflo(v.w) * sc;
            }
        }
        const int sw = ((rr >> 2) & 3) << 3;
        float* dp = &Xs[rr * 128 + (k0 ^ sw)];
        dp[0] = v0; dp[1] = v1; dp[2] = v2; dp[3] = v3;
    }
    __syncthreads();

    const int jt = (tid & 15) * 8;
    const int rt = (tid >> 4) * 4;
    const int sw = ((tid >> 4) & 3) << 3;
    float acc[4][8];
#pragma unroll
    for (int i = 0; i < 4; ++i)
#pragma unroll
        for (int j = 0; j < 8; ++j) acc[i][j] = 0.f;

    for (int k = 0; k < 128; ++k) {
        const int kk = k ^ sw;
        float a0 = Xs[(rt + 0) * 128 + kk];
        float a1 = Xs[(rt + 1) * 128 + kk];
        float a2 = Xs[(rt + 2) * 128 + kk];
        float a3 = Xs[(rt + 3) * 128 + kk];
        const uint4 bw = *(const uint4*)&Ws[k * 128 + jt];
        float b[8];
        b[0] = bflo(bw.x); b[1] = bfhi(bw.x);
        b[2] = bflo(bw.y); b[3] = bfhi(bw.y);
        b[4] = bflo(bw.z); b[5] = bfhi(bw.z);
        b[6] = bflo(bw.w); b[7] = bfhi(bw.w);
#pragma unroll
        for (int j = 0; j < 8; ++j) {
            acc[0][j] = fmaf(a0, b[j], acc[0][j]);
            acc[1][j] = fmaf(a1, b[j], acc[1][j]);
            acc[2][j] = fmaf(a2, b[j], acc[2][j]);
            acc[3][j] = fmaf(a3, b[j], acc[3][j]);
        }
    }

#pragma unroll
    for (int i = 0; i < 4; ++i) {
        const int r = r0 + rt + i;
        if (r < N) {
            uint4 o;
            o.x = packbf(acc[i][0], acc[i][1]);
            o.y = packbf(acc[i][2], acc[i][3]);
            o.z = packbf(acc[i][4], acc[i][5]);
            o.w = packbf(acc[i][6], acc[i][7]);
            *(uint4*)&out[(size_t)r * 128 + jt] = o;
        }
    }
}

// ---------------- CSR aggregation (one wave per dst node) ----------------
template <int FINAL>
__global__ __launch_bounds__(256) void spmm_agg(const unsigned short* __restrict__ T,
                                                const int* __restrict__ row_ptr,
                                                const int* __restrict__ ssrc,
                                                const float* __restrict__ in_norm,
                                                const float* __restrict__ bias,
                                                unsigned short* __restrict__ Hout,
                                                const unsigned short* __restrict__ Res,
                                                const float* __restrict__ mlpW,
                                                const float* __restrict__ mlpB,
                                                float* __restrict__ out, int N) {
    const int lane = threadIdx.x & 63;
    const int d = blockIdx.x * 4 + (threadIdx.x >> 6);
    if (d >= N) return;

    const int start = row_ptr[d], end = row_ptr[d + 1];
    float ax = 0.f, ay = 0.f;
    const unsigned int* T32 = (const unsigned int*)T;

    for (int base = start; base < end; base += 64) {
        const int cnt = min(64, end - base);
        int sl = (lane < cnt) ? ssrc[base + lane] : 0;
        int i = 0;
        for (; i + 4 <= cnt; i += 4) {
            int s0 = __shfl(sl, i + 0);
            int s1 = __shfl(sl, i + 1);
            int s2 = __shfl(sl, i + 2);
            int s3 = __shfl(sl, i + 3);
            unsigned int w0 = T32[(size_t)s0 * 64 + lane];
            unsigned int w1 = T32[(size_t)s1 * 64 + lane];
            unsigned int w2 = T32[(size_t)s2 * 64 + lane];
            unsigned int w3 = T32[(size_t)s3 * 64 + lane];
            ax += bflo(w0) + bflo(w1) + bflo(w2) + bflo(w3);
            ay += bfhi(w0) + bfhi(w1) + bfhi(w2) + bfhi(w3);
        }
        for (; i < cnt; ++i) {
            int s = __shfl(sl, i);
            unsigned int w = T32[(size_t)s * 64 + lane];
            ax += bflo(w);
            ay += bfhi(w);
        }
    }

    const float inr = in_norm[d];
    const float2 bb = ((const float2*)bias)[lane];
    float vx = ax * inr + bb.x;
    float vy = ay * inr + bb.y;

    if constexpr (FINAL == 0) {
        vx = fmaxf(vx, 0.f);
        vy = fmaxf(vy, 0.f);
        ((unsigned int*)Hout)[(size_t)d * 64 + lane] = packbf(vx, vy);
    } else {
        unsigned int rw = ((const unsigned int*)Res)[(size_t)d * 64 + lane];
        vx += bflo(rw);
        vy += bfhi(rw);
        const float4 mw = ((const float4*)mlpW)[lane];
        float p0 = vx * mw.x + vy * mw.z;
        float p1 = vx * mw.y + vy * mw.w;
#pragma unroll
        for (int off = 32; off > 0; off >>= 1) {
            p0 += __shfl_xor(p0, off);
            p1 += __shfl_xor(p1, off);
        }
        if (lane == 0) {
            out[(size_t)d * 2 + 0] = p0 + mlpB[0];
            out[(size_t)d * 2 + 1] = p1 + mlpB[1];
        }
    }
}

// ---------------- launch ----------------
extern "C" void kernel_launch(void* const* d_in, const int* in_sizes, int n_in,
                              void* d_out, int out_size, void* d_ws, size_t ws_size,
                              hipStream_t stream) {
    const float* x     = (const float*)d_in[0];
    const int*   src   = (const int*)d_in[1];
    const int*   dst   = (const int*)d_in[2];
    const float* W1    = (const float*)d_in[3];
    const float* b1    = (const float*)d_in[4];
    const float* W2    = (const float*)d_in[5];
    const float* b2    = (const float*)d_in[6];
    const float* res_W = (const float*)d_in[7];
    const float* mlp_W = (const float*)d_in[8];
    const float* mlp_b = (const float*)d_in[9];
    float* out = (float*)d_out;

    const int N = in_sizes[0] / 128;
    const int E = in_sizes[1];
    const int EPS = (E + NSLICE - 1) / NSLICE;
    const size_t PARTIAL_WORDS = (size_t)NR_PAD * NSLICE * (RANGE / 2);

    // workspace layout. partialS aliases A (A is dead until the first gemm,
    // which runs after k_deg_reduce has consumed partialS).
    char* p = (char*)d_ws;
    unsigned short* A = (unsigned short*)p;  p += (size_t)N * 128 * 2;   // 25.6 MB >= partialS 16.8 MB
    unsigned short* B = (unsigned short*)p;  p += (size_t)N * 128 * 2;
    unsigned int* partialD = (unsigned int*)p; p += PARTIAL_WORDS * 4;
    float* out_norm = (float*)p;             p += (size_t)N * 4;
    float* in_norm  = (float*)p;             p += (size_t)N * 4;
    int* in_deg     = (int*)p;               p += (size_t)N * 4;
    int* row_ptr    = (int*)p;               p += (size_t)(N + 1) * 4;
    int* scanpart   = (int*)p;               p += (size_t)1024 * 4;
    int* ssrc       = (int*)p;               p += (size_t)E * 4;
    unsigned int* partialS = (unsigned int*)A;

    const int gN = (N + 255) / 256;
    const int nb = (N + 1023) / 1024;
    const int gGemm = (N + 63) / 64;
    const int gSpmm = (N + 3) / 4;

    // 1. degrees + norms + slice prefixes (no global atomics)
    k_hist_lds<<<dim3(NR_PAD * NSLICE, 2), 256, 0, stream>>>(src, dst, partialS, partialD, E, EPS);
    k_deg_reduce<<<dim3(NR_PAD * (RANGE / 2) / 256, 2), 256, 0, stream>>>(partialS, partialD,
                                                                          out_norm, in_norm, in_deg, N);

    // 2. row_ptr scan + deterministic CSR scatter
    k_scan_block<<<nb, 1024, 0, stream>>>(in_deg, row_ptr, scanpart, N);
    k_scan_partials<<<1, 1024, 0, stream>>>(scanpart, nb);
    k_scan_finalize<<<gN, 256, 0, stream>>>(row_ptr, scanpart, N);
    k_scatter_lds<<<NR_PAD * NSLICE, 256, 0, stream>>>(src, dst, partialD, row_ptr, ssrc, E, EPS);

    // 3. layer 1: t1 = (x * out_norm) @ W1 -> A ; h1 = relu(agg*in_norm + b1) -> B
    gemm128<float><<<gGemm, 256, 0, stream>>>(x, out_norm, W1, A, N);
    spmm_agg<0><<<gSpmm, 256, 0, stream>>>(A, row_ptr, ssrc, in_norm, b1, B,
                                           (const unsigned short*)nullptr, nullptr, nullptr,
                                           nullptr, N);

    // 4. layer 2: t2 = (h1 * out_norm) @ W2 -> A ; res = x @ res_W -> B
    gemm128<unsigned short><<<gGemm, 256, 0, stream>>>(B, out_norm, W2, A, N);
    gemm128<float><<<gGemm, 256, 0, stream>>>(x, (const float*)nullptr, res_W, B, N);

    // 5. final aggregation + residual + MLP head -> out
    spmm_agg<1><<<gSpmm, 256, 0, stream>>>(A, row_ptr, ssrc, in_norm, b2, nullptr,
                                           B, mlp_W, mlp_b, out, N);

    (void)n_in; (void)out_size; (void)ws_size;
}

// Round 4
// 362.461 us; speedup vs baseline: 1.8405x; 1.3778x over previous
//
#include <hip/hip_runtime.h>
#include <stdint.h>

// ---------------- bf16 helpers (raw ushort storage) ----------------
__device__ __forceinline__ float bflo(unsigned int u) {
    union { unsigned int u; float f; } c; c.u = u << 16; return c.f;
}
__device__ __forceinline__ float bfhi(unsigned int u) {
    union { unsigned int u; float f; } c; c.u = u & 0xffff0000u; return c.f;
}
__device__ __forceinline__ unsigned int f2bf(float f) {
    union { float f; unsigned int u; } c; c.f = f;
    unsigned int u = c.u;
    u += 0x7fffu + ((u >> 16) & 1u);   // round-to-nearest-even
    return u >> 16;
}
__device__ __forceinline__ unsigned int packbf(float a, float b) {
    return f2bf(a) | (f2bf(b) << 16);
}

typedef __attribute__((ext_vector_type(8))) short s8v;   // 8 bf16 (4 VGPRs)
typedef __attribute__((ext_vector_type(4))) float f4v;   // MFMA accumulator

__device__ __forceinline__ f4v mfma16(s8v a, s8v b, f4v c) {
    return __builtin_amdgcn_mfma_f32_16x16x32_bf16(a, b, c, 0, 0, 0);
}

// ---------------- counting-sort parameters ----------------
#define RANGE_BITS 14
#define RANGE (1 << RANGE_BITS)     // 16384 nodes per LDS range (32 KB @ 2B/node)
#define NR_PAD 8                    // ranges padded to 8 for XCD swizzle (range = bid & 7)
#define NSLICE 64                   // edge slices; per-slice count <= E/64 = 25000 < 2^16

// ---------------- weight prep: W[k][n] f32 -> Wt[n][k] bf16 ----------------
// grid (3, 4): x picks matrix, y picks k-quarter. Coalesced reads, packed b32 writes.
__global__ __launch_bounds__(256) void k_prep_w(const float* __restrict__ W1,
                                                const float* __restrict__ W2,
                                                const float* __restrict__ Wr,
                                                unsigned short* __restrict__ Wt) {
    const float* W = (blockIdx.x == 0) ? W1 : (blockIdx.x == 1) ? W2 : Wr;
    unsigned short* T = Wt + (size_t)blockIdx.x * 16384;
    const int wv = threadIdx.x >> 6, l = threadIdx.x & 63;
    const int kb = blockIdx.y * 32 + wv * 8;
#pragma unroll
    for (int half = 0; half < 2; ++half) {
        const int n = l + half * 64;
        unsigned short tmp[8];
#pragma unroll
        for (int j = 0; j < 8; ++j) tmp[j] = (unsigned short)f2bf(W[(size_t)(kb + j) * 128 + n]);
#pragma unroll
        for (int j = 0; j < 8; j += 2)
            *(unsigned int*)&T[(size_t)n * 128 + kb + j] =
                (unsigned int)tmp[j] | ((unsigned int)tmp[j + 1] << 16);
    }
}

// ---------------- LDS-privatized degree histogram (no global atomics) ----------------
__global__ __launch_bounds__(256) void k_hist_lds(const int* __restrict__ src,
                                                  const int* __restrict__ dst,
                                                  unsigned int* __restrict__ partialS,
                                                  unsigned int* __restrict__ partialD,
                                                  int E, int EPS) {
    __shared__ unsigned int cnt[RANGE / 2];   // 32 KB
    const int r = blockIdx.x & 7;
    const int s = blockIdx.x >> 3;
    const int a = blockIdx.y;
    const int* __restrict__ arr = a ? dst : src;
    unsigned int* part = (a ? partialD : partialS)
                         + ((size_t)r * NSLICE + s) * (RANGE / 2);
    for (int i = threadIdx.x; i < RANGE / 2; i += 256) cnt[i] = 0;
    __syncthreads();
    const int e0 = s * EPS;
    const int e1 = min(E, e0 + EPS);
    int e = e0 + threadIdx.x * 4;
    for (; e + 3 < e1; e += 1024) {
        const int4 v = *(const int4*)&arr[e];
        if ((v.x >> RANGE_BITS) == r) { int l = v.x & (RANGE - 1); atomicAdd(&cnt[l >> 1], 1u << ((l & 1) << 4)); }
        if ((v.y >> RANGE_BITS) == r) { int l = v.y & (RANGE - 1); atomicAdd(&cnt[l >> 1], 1u << ((l & 1) << 4)); }
        if ((v.z >> RANGE_BITS) == r) { int l = v.z & (RANGE - 1); atomicAdd(&cnt[l >> 1], 1u << ((l & 1) << 4)); }
        if ((v.w >> RANGE_BITS) == r) { int l = v.w & (RANGE - 1); atomicAdd(&cnt[l >> 1], 1u << ((l & 1) << 4)); }
    }
    for (; e < e1; ++e) {
        const int idx = arr[e];
        if ((idx >> RANGE_BITS) == r) { int l = idx & (RANGE - 1); atomicAdd(&cnt[l >> 1], 1u << ((l & 1) << 4)); }
    }
    __syncthreads();
    for (int i = threadIdx.x; i < RANGE / 2; i += 256) part[i] = cnt[i];
}

// ---------------- reduce partials -> degrees/norms; dst partials -> slice prefixes ----------------
__global__ __launch_bounds__(256) void k_deg_reduce(unsigned int* __restrict__ pS,
                                                    unsigned int* __restrict__ pD,
                                                    float* __restrict__ out_norm,
                                                    float* __restrict__ in_norm,
                                                    int* __restrict__ in_deg, int N) {
    const int a = blockIdx.y;
    const int t = blockIdx.x * 256 + threadIdx.x;
    const int r = t >> (RANGE_BITS - 1);
    const int w = t & ((RANGE / 2) - 1);
    unsigned int* base = (a ? pD : pS) + (size_t)r * NSLICE * (RANGE / 2) + w;
    unsigned int lo = 0, hi = 0;
    if (a) {
        for (int s = 0; s < NSLICE; ++s) {
            const unsigned int v = base[(size_t)s * (RANGE / 2)];
            base[(size_t)s * (RANGE / 2)] = lo | (hi << 16);
            lo += v & 0xffffu; hi += v >> 16;
        }
    } else {
        for (int s = 0; s < NSLICE; ++s) {
            const unsigned int v = base[(size_t)s * (RANGE / 2)];
            lo += v & 0xffffu; hi += v >> 16;
        }
    }
    const int n0 = r * RANGE + 2 * w, n1 = n0 + 1;
    if (a) {
        if (n0 < N) { in_deg[n0] = (int)lo; in_norm[n0] = rsqrtf(fmaxf((float)lo, 1.f)); }
        if (n1 < N) { in_deg[n1] = (int)hi; in_norm[n1] = rsqrtf(fmaxf((float)hi, 1.f)); }
    } else {
        if (n0 < N) out_norm[n0] = rsqrtf(fmaxf((float)lo, 1.f));
        if (n1 < N) out_norm[n1] = rsqrtf(fmaxf((float)hi, 1.f));
    }
}

// ---------------- prefix-sum (3-phase) ----------------
__global__ __launch_bounds__(1024) void k_scan_block(const int* __restrict__ in,
                                                     int* __restrict__ row_ptr,
                                                     int* __restrict__ partials, int n) {
    __shared__ int sh[1024];
    int i = blockIdx.x * 1024 + threadIdx.x;
    int v = (i < n) ? in[i] : 0;
    sh[threadIdx.x] = v;
    __syncthreads();
    for (int off = 1; off < 1024; off <<= 1) {
        int t = (threadIdx.x >= off) ? sh[threadIdx.x - off] : 0;
        __syncthreads();
        sh[threadIdx.x] += t;
        __syncthreads();
    }
    if (i < n) row_ptr[i + 1] = sh[threadIdx.x];
    if (threadIdx.x == 1023) partials[blockIdx.x] = sh[1023];
}

__global__ __launch_bounds__(1024) void k_scan_partials(int* __restrict__ partials, int nb) {
    __shared__ int sh[1024];
    int v = (threadIdx.x < nb) ? partials[threadIdx.x] : 0;
    sh[threadIdx.x] = v;
    __syncthreads();
    for (int off = 1; off < 1024; off <<= 1) {
        int t = (threadIdx.x >= off) ? sh[threadIdx.x - off] : 0;
        __syncthreads();
        sh[threadIdx.x] += t;
        __syncthreads();
    }
    if (threadIdx.x < nb) partials[threadIdx.x] = sh[threadIdx.x] - v;
}

__global__ void k_scan_finalize(int* __restrict__ row_ptr, const int* __restrict__ partials,
                                int n) {
    int i = blockIdx.x * blockDim.x + threadIdx.x;
    if (i < n) {
        row_ptr[i + 1] += partials[i >> 10];
        if (i == 0) row_ptr[0] = 0;
    }
}

// ---------------- deterministic CSR scatter (no global atomics) ----------------
__global__ __launch_bounds__(256) void k_scatter_lds(const int* __restrict__ src,
                                                     const int* __restrict__ dst,
                                                     const unsigned int* __restrict__ pD,
                                                     const int* __restrict__ row_ptr,
                                                     int* __restrict__ ssrc, int E, int EPS) {
    __shared__ unsigned int cur[RANGE / 2];   // 32 KB
    const int r = blockIdx.x & 7;
    const int s = blockIdx.x >> 3;
    const unsigned int* pre = pD + ((size_t)r * NSLICE + s) * (RANGE / 2);
    for (int i = threadIdx.x; i < RANGE / 2; i += 256) cur[i] = pre[i];
    __syncthreads();
    const int e0 = s * EPS;
    const int e1 = min(E, e0 + EPS);
    int e = e0 + threadIdx.x * 4;
    for (; e + 3 < e1; e += 1024) {
        const int4 v = *(const int4*)&dst[e];
#pragma unroll
        for (int j = 0; j < 4; ++j) {
            const int d = (&v.x)[j];
            if ((d >> RANGE_BITS) == r) {
                const int local = d & (RANGE - 1);
                const int sh = (local & 1) << 4;
                const unsigned int old = atomicAdd(&cur[local >> 1], 1u << sh);
                const unsigned int off = (old >> sh) & 0xffffu;
                ssrc[row_ptr[d] + (int)off] = src[e + j];
            }
        }
    }
    for (; e < e1; ++e) {
        const int d = dst[e];
        if ((d >> RANGE_BITS) == r) {
            const int local = d & (RANGE - 1);
            const int sh = (local & 1) << 4;
            const unsigned int old = atomicAdd(&cur[local >> 1], 1u << sh);
            const unsigned int off = (old >> sh) & 0xffffu;
            ssrc[row_ptr[d] + (int)off] = src[e];
        }
    }
}

// ---------------- MFMA GEMM: out_w[N,128](bf16) = rowscale?(X @ W_w) ----------------
// Block: 64 rows x 128 cols, 4 waves (16 rows each). K=128 = 4 MFMA k-steps.
// W^T staged in LDS bf16 with XOR-swizzled 16B blocks (conflict-free ds_read_b128).
// A-fragments loaded straight from global (64B/row segments). Row-scale applied in
// epilogue (diag(s)·X@W == diag(s)·(X@W)) so gemm1/gemm3 share the raw-x A operand.
template <typename TIN, int NW, bool SCALE0>
__global__ __launch_bounds__(256) void gemm_mfma(const TIN* __restrict__ X,
                                                 const unsigned short* __restrict__ Wt0,
                                                 const unsigned short* __restrict__ Wt1,
                                                 const float* __restrict__ scale,
                                                 unsigned short* __restrict__ out0,
                                                 unsigned short* __restrict__ out1,
                                                 int N) {
    __shared__ unsigned short Ws[NW][128 * 128];   // 32 KB per weight (64 KB max)
    const int tid = threadIdx.x;
#pragma unroll
    for (int w = 0; w < NW; ++w) {
        const unsigned short* Wsrc = w ? Wt1 : Wt0;
        for (int i = tid; i < 2048; i += 256) {
            const int n = i >> 4, b = i & 15;
            const uint4 v = *(const uint4*)&Wsrc[(size_t)n * 128 + b * 8];
            *(uint4*)&Ws[w][n * 128 + ((b ^ (n & 15)) << 3)] = v;
        }
    }
    __syncthreads();

    const int lane = tid & 63;
    const int wave = tid >> 6;
    const int quad = lane >> 4;
    const int l16 = lane & 15;
    const int r_base = blockIdx.x * 64 + wave * 16;
    const int ra = min(r_base + l16, N - 1);          // A-operand row (clamped)

    f4v acc[NW][8];
#pragma unroll
    for (int w = 0; w < NW; ++w)
#pragma unroll
        for (int nn = 0; nn < 8; ++nn) acc[w][nn] = (f4v)0.f;

    const TIN* xp = X + (size_t)ra * 128 + quad * 8;

#pragma unroll
    for (int kt = 0; kt < 4; ++kt) {
        s8v af;
        if constexpr (sizeof(TIN) == 4) {
            const float4 lo = *(const float4*)(xp + kt * 32);
            const float4 hi = *(const float4*)(xp + kt * 32 + 4);
            af[0] = (short)f2bf(lo.x); af[1] = (short)f2bf(lo.y);
            af[2] = (short)f2bf(lo.z); af[3] = (short)f2bf(lo.w);
            af[4] = (short)f2bf(hi.x); af[5] = (short)f2bf(hi.y);
            af[6] = (short)f2bf(hi.z); af[7] = (short)f2bf(hi.w);
        } else {
            af = *(const s8v*)(xp + kt * 32);
        }
#pragma unroll
        for (int nn = 0; nn < 8; ++nn) {
            const int bofs = (nn * 16 + l16) * 128 + (((kt * 4 + quad) ^ l16) << 3);
#pragma unroll
            for (int w = 0; w < NW; ++w) {
                const s8v bf = *(const s8v*)&Ws[w][bofs];
                acc[w][nn] = mfma16(af, bf, acc[w][nn]);
            }
        }
    }

    // epilogue: C/D layout col = lane&15, row = quad*4 + reg
    const int rc = r_base + quad * 4;
    float sc[4];
    if constexpr (SCALE0) {
#pragma unroll
        for (int g = 0; g < 4; ++g) sc[g] = scale[min(rc + g, N - 1)];
    }
#pragma unroll
    for (int nn = 0; nn < 8; ++nn) {
        const int col = nn * 16 + l16;
#pragma unroll
        for (int g = 0; g < 4; ++g) {
            const int r = rc + g;
            if (r < N) {
                float v0 = acc[0][nn][g];
                if constexpr (SCALE0) v0 *= sc[g];
                out0[(size_t)r * 128 + col] = (unsigned short)f2bf(v0);
                if constexpr (NW == 2)
                    out1[(size_t)r * 128 + col] = (unsigned short)f2bf(acc[1][nn][g]);
            }
        }
    }
}

// ---------------- CSR aggregation (one wave per dst node) ----------------
template <int FINAL>
__global__ __launch_bounds__(256) void spmm_agg(const unsigned short* __restrict__ T,
                                                const int* __restrict__ row_ptr,
                                                const int* __restrict__ ssrc,
                                                const float* __restrict__ in_norm,
                                                const float* __restrict__ bias,
                                                unsigned short* __restrict__ Hout,
                                                const unsigned short* __restrict__ Res,
                                                const float* __restrict__ mlpW,
                                                const float* __restrict__ mlpB,
                                                float* __restrict__ out, int N) {
    const int lane = threadIdx.x & 63;
    const int d = blockIdx.x * 4 + (threadIdx.x >> 6);
    if (d >= N) return;

    const int start = row_ptr[d], end = row_ptr[d + 1];
    float ax = 0.f, ay = 0.f;
    const unsigned int* T32 = (const unsigned int*)T;

    for (int base = start; base < end; base += 64) {
        const int cnt = min(64, end - base);
        int sl = (lane < cnt) ? ssrc[base + lane] : 0;
        int i = 0;
        for (; i + 4 <= cnt; i += 4) {
            int s0 = __shfl(sl, i + 0);
            int s1 = __shfl(sl, i + 1);
            int s2 = __shfl(sl, i + 2);
            int s3 = __shfl(sl, i + 3);
            unsigned int w0 = T32[(size_t)s0 * 64 + lane];
            unsigned int w1 = T32[(size_t)s1 * 64 + lane];
            unsigned int w2 = T32[(size_t)s2 * 64 + lane];
            unsigned int w3 = T32[(size_t)s3 * 64 + lane];
            ax += bflo(w0) + bflo(w1) + bflo(w2) + bflo(w3);
            ay += bfhi(w0) + bfhi(w1) + bfhi(w2) + bfhi(w3);
        }
        for (; i < cnt; ++i) {
            int s = __shfl(sl, i);
            unsigned int w = T32[(size_t)s * 64 + lane];
            ax += bflo(w);
            ay += bfhi(w);
        }
    }

    const float inr = in_norm[d];
    const float2 bb = ((const float2*)bias)[lane];
    float vx = ax * inr + bb.x;
    float vy = ay * inr + bb.y;

    if constexpr (FINAL == 0) {
        vx = fmaxf(vx, 0.f);
        vy = fmaxf(vy, 0.f);
        ((unsigned int*)Hout)[(size_t)d * 64 + lane] = packbf(vx, vy);
    } else {
        unsigned int rw = ((const unsigned int*)Res)[(size_t)d * 64 + lane];
        vx += bflo(rw);
        vy += bfhi(rw);
        const float4 mw = ((const float4*)mlpW)[lane];
        float p0 = vx * mw.x + vy * mw.z;
        float p1 = vx * mw.y + vy * mw.w;
#pragma unroll
        for (int off = 32; off > 0; off >>= 1) {
            p0 += __shfl_xor(p0, off);
            p1 += __shfl_xor(p1, off);
        }
        if (lane == 0) {
            out[(size_t)d * 2 + 0] = p0 + mlpB[0];
            out[(size_t)d * 2 + 1] = p1 + mlpB[1];
        }
    }
}

// ---------------- launch ----------------
extern "C" void kernel_launch(void* const* d_in, const int* in_sizes, int n_in,
                              void* d_out, int out_size, void* d_ws, size_t ws_size,
                              hipStream_t stream) {
    const float* x     = (const float*)d_in[0];
    const int*   src   = (const int*)d_in[1];
    const int*   dst   = (const int*)d_in[2];
    const float* W1    = (const float*)d_in[3];
    const float* W2    = (const float*)d_in[5];
    const float* b1    = (const float*)d_in[4];
    const float* b2    = (const float*)d_in[6];
    const float* res_W = (const float*)d_in[7];
    const float* mlp_W = (const float*)d_in[8];
    const float* mlp_b = (const float*)d_in[9];
    float* out = (float*)d_out;

    const int N = in_sizes[0] / 128;
    const int E = in_sizes[1];
    const int EPS = (E + NSLICE - 1) / NSLICE;
    const size_t PARTIAL_WORDS = (size_t)NR_PAD * NSLICE * (RANGE / 2);  // 4.19M words

    // workspace layout. partialS aliases A, partialD aliases C: both are dead
    // before the first GEMM writes A/C (deg_reduce & scatter consume them earlier).
    char* p = (char*)d_ws;
    unsigned short* A = (unsigned short*)p;  p += (size_t)N * 128 * 2;   // t1 / t2 (25.6 MB >= 16.8 MB partial)
    unsigned short* B = (unsigned short*)p;  p += (size_t)N * 128 * 2;   // h1
    unsigned short* C = (unsigned short*)p;  p += (size_t)N * 128 * 2;   // res   (aliases partialD)
    unsigned short* Wt = (unsigned short*)p; p += (size_t)3 * 16384 * 2; // Wt1|Wt2|Rt bf16
    float* out_norm = (float*)p;             p += (size_t)N * 4;
    float* in_norm  = (float*)p;             p += (size_t)N * 4;
    int* in_deg     = (int*)p;               p += (size_t)N * 4;
    int* row_ptr    = (int*)p;               p += (size_t)(N + 1) * 4;
    int* scanpart   = (int*)p;               p += (size_t)1024 * 4;
    int* ssrc       = (int*)p;               p += (size_t)E * 4;
    unsigned int* partialS = (unsigned int*)A;
    unsigned int* partialD = (unsigned int*)C;
    (void)PARTIAL_WORDS;

    const int gN = (N + 255) / 256;
    const int nb = (N + 1023) / 1024;
    const int gGemm = (N + 63) / 64;
    const int gSpmm = (N + 3) / 4;

    // 0. weights -> transposed bf16
    k_prep_w<<<dim3(3, 4), 256, 0, stream>>>(W1, W2, res_W, Wt);

    // 1. degrees + norms + slice prefixes (no global atomics)
    k_hist_lds<<<dim3(NR_PAD * NSLICE, 2), 256, 0, stream>>>(src, dst, partialS, partialD, E, EPS);
    k_deg_reduce<<<dim3(NR_PAD * (RANGE / 2) / 256, 2), 256, 0, stream>>>(partialS, partialD,
                                                                          out_norm, in_norm, in_deg, N);

    // 2. row_ptr scan + deterministic CSR scatter
    k_scan_block<<<nb, 1024, 0, stream>>>(in_deg, row_ptr, scanpart, N);
    k_scan_partials<<<1, 1024, 0, stream>>>(scanpart, nb);
    k_scan_finalize<<<gN, 256, 0, stream>>>(row_ptr, scanpart, N);
    k_scatter_lds<<<NR_PAD * NSLICE, 256, 0, stream>>>(src, dst, partialD, row_ptr, ssrc, E, EPS);

    // 3. fused gemm1+gemm3: A = rowscale(x@W1, out_norm), C = x@res_W
    gemm_mfma<float, 2, true><<<gGemm, 256, 0, stream>>>(x, Wt, Wt + 2 * 16384, out_norm, A, C, N);

    // 4. layer-1 aggregation: B = relu(agg(A)*in_norm + b1)
    spmm_agg<0><<<gSpmm, 256, 0, stream>>>(A, row_ptr, ssrc, in_norm, b1, B,
                                           (const unsigned short*)nullptr, nullptr, nullptr,
                                           nullptr, N);

    // 5. gemm2: A = rowscale(B@W2, out_norm)
    gemm_mfma<unsigned short, 1, true><<<gGemm, 256, 0, stream>>>(B, Wt + 16384, nullptr,
                                                                  out_norm, A, nullptr, N);

    // 6. final aggregation + residual + MLP head -> out
    spmm_agg<1><<<gSpmm, 256, 0, stream>>>(A, row_ptr, ssrc, in_norm, b2, nullptr,
                                           C, mlp_W, mlp_b, out, N);

    (void)n_in; (void)out_size; (void)ws_size;
}

// Round 5
// 358.361 us; speedup vs baseline: 1.8615x; 1.0114x over previous
//
#include <hip/hip_runtime.h>
#include <stdint.h>

// ---------------- bf16 helpers (raw ushort storage) ----------------
__device__ __forceinline__ float bflo(unsigned int u) {
    union { unsigned int u; float f; } c; c.u = u << 16; return c.f;
}
__device__ __forceinline__ float bfhi(unsigned int u) {
    union { unsigned int u; float f; } c; c.u = u & 0xffff0000u; return c.f;
}
__device__ __forceinline__ unsigned int f2bf(float f) {
    union { float f; unsigned int u; } c; c.f = f;
    unsigned int u = c.u;
    u += 0x7fffu + ((u >> 16) & 1u);   // round-to-nearest-even
    return u >> 16;
}
__device__ __forceinline__ unsigned int packbf(float a, float b) {
    return f2bf(a) | (f2bf(b) << 16);
}

typedef __attribute__((ext_vector_type(8))) short s8v;   // 8 bf16 (4 VGPRs)
typedef __attribute__((ext_vector_type(4))) float f4v;   // MFMA accumulator

__device__ __forceinline__ f4v mfma16(s8v a, s8v b, f4v c) {
    return __builtin_amdgcn_mfma_f32_16x16x32_bf16(a, b, c, 0, 0, 0);
}

// ---------------- counting-sort parameters ----------------
#define RANGE_BITS 14
#define RANGE (1 << RANGE_BITS)     // 16384 nodes per LDS range (32 KB @ 2B/node)
#define NR_PAD 8                    // ranges padded to 8 for XCD swizzle (range = bid & 7)
#define NSLICE 64                   // edge slices; per-slice count <= E/64 = 25000 < 2^16

// ---------------- weight prep: W[k][n] f32 -> Wt[n][k] bf16 ----------------
__global__ __launch_bounds__(256) void k_prep_w(const float* __restrict__ W1,
                                                const float* __restrict__ W2,
                                                const float* __restrict__ Wr,
                                                unsigned short* __restrict__ Wt) {
    const float* W = (blockIdx.x == 0) ? W1 : (blockIdx.x == 1) ? W2 : Wr;
    unsigned short* T = Wt + (size_t)blockIdx.x * 16384;
    const int wv = threadIdx.x >> 6, l = threadIdx.x & 63;
    const int kb = blockIdx.y * 32 + wv * 8;
#pragma unroll
    for (int half = 0; half < 2; ++half) {
        const int n = l + half * 64;
        unsigned short tmp[8];
#pragma unroll
        for (int j = 0; j < 8; ++j) tmp[j] = (unsigned short)f2bf(W[(size_t)(kb + j) * 128 + n]);
#pragma unroll
        for (int j = 0; j < 8; j += 2)
            *(unsigned int*)&T[(size_t)n * 128 + kb + j] =
                (unsigned int)tmp[j] | ((unsigned int)tmp[j + 1] << 16);
    }
}

// ---------------- LDS-privatized degree histogram (no global atomics) ----------------
__global__ __launch_bounds__(256) void k_hist_lds(const int* __restrict__ src,
                                                  const int* __restrict__ dst,
                                                  unsigned int* __restrict__ partialS,
                                                  unsigned int* __restrict__ partialD,
                                                  int E, int EPS) {
    __shared__ unsigned int cnt[RANGE / 2];   // 32 KB
    const int r = blockIdx.x & 7;
    const int s = blockIdx.x >> 3;
    const int a = blockIdx.y;
    const int* __restrict__ arr = a ? dst : src;
    unsigned int* part = (a ? partialD : partialS)
                         + ((size_t)r * NSLICE + s) * (RANGE / 2);
    for (int i = threadIdx.x; i < RANGE / 2; i += 256) cnt[i] = 0;
    __syncthreads();
    const int e0 = s * EPS;
    const int e1 = min(E, e0 + EPS);
    int e = e0 + threadIdx.x * 4;
    for (; e + 3 < e1; e += 1024) {
        const int4 v = *(const int4*)&arr[e];
        if ((v.x >> RANGE_BITS) == r) { int l = v.x & (RANGE - 1); atomicAdd(&cnt[l >> 1], 1u << ((l & 1) << 4)); }
        if ((v.y >> RANGE_BITS) == r) { int l = v.y & (RANGE - 1); atomicAdd(&cnt[l >> 1], 1u << ((l & 1) << 4)); }
        if ((v.z >> RANGE_BITS) == r) { int l = v.z & (RANGE - 1); atomicAdd(&cnt[l >> 1], 1u << ((l & 1) << 4)); }
        if ((v.w >> RANGE_BITS) == r) { int l = v.w & (RANGE - 1); atomicAdd(&cnt[l >> 1], 1u << ((l & 1) << 4)); }
    }
    for (; e < e1; ++e) {
        const int idx = arr[e];
        if ((idx >> RANGE_BITS) == r) { int l = idx & (RANGE - 1); atomicAdd(&cnt[l >> 1], 1u << ((l & 1) << 4)); }
    }
    __syncthreads();
    for (int i = threadIdx.x; i < RANGE / 2; i += 256) part[i] = cnt[i];
}

// ---------------- reduce partials -> degrees/norms; dst partials -> slice prefixes ----------------
__global__ __launch_bounds__(256) void k_deg_reduce(unsigned int* __restrict__ pS,
                                                    unsigned int* __restrict__ pD,
                                                    float* __restrict__ out_norm,
                                                    float* __restrict__ in_norm,
                                                    int* __restrict__ in_deg, int N) {
    const int a = blockIdx.y;
    const int t = blockIdx.x * 256 + threadIdx.x;
    const int r = t >> (RANGE_BITS - 1);
    const int w = t & ((RANGE / 2) - 1);
    unsigned int* base = (a ? pD : pS) + (size_t)r * NSLICE * (RANGE / 2) + w;
    unsigned int lo = 0, hi = 0;
    if (a) {
        for (int s = 0; s < NSLICE; ++s) {
            const unsigned int v = base[(size_t)s * (RANGE / 2)];
            base[(size_t)s * (RANGE / 2)] = lo | (hi << 16);
            lo += v & 0xffffu; hi += v >> 16;
        }
    } else {
        for (int s = 0; s < NSLICE; ++s) {
            const unsigned int v = base[(size_t)s * (RANGE / 2)];
            lo += v & 0xffffu; hi += v >> 16;
        }
    }
    const int n0 = r * RANGE + 2 * w, n1 = n0 + 1;
    if (a) {
        if (n0 < N) { in_deg[n0] = (int)lo; in_norm[n0] = rsqrtf(fmaxf((float)lo, 1.f)); }
        if (n1 < N) { in_deg[n1] = (int)hi; in_norm[n1] = rsqrtf(fmaxf((float)hi, 1.f)); }
    } else {
        if (n0 < N) out_norm[n0] = rsqrtf(fmaxf((float)lo, 1.f));
        if (n1 < N) out_norm[n1] = rsqrtf(fmaxf((float)hi, 1.f));
    }
}

// ---------------- prefix-sum (3-phase) ----------------
__global__ __launch_bounds__(1024) void k_scan_block(const int* __restrict__ in,
                                                     int* __restrict__ row_ptr,
                                                     int* __restrict__ partials, int n) {
    __shared__ int sh[1024];
    int i = blockIdx.x * 1024 + threadIdx.x;
    int v = (i < n) ? in[i] : 0;
    sh[threadIdx.x] = v;
    __syncthreads();
    for (int off = 1; off < 1024; off <<= 1) {
        int t = (threadIdx.x >= off) ? sh[threadIdx.x - off] : 0;
        __syncthreads();
        sh[threadIdx.x] += t;
        __syncthreads();
    }
    if (i < n) row_ptr[i + 1] = sh[threadIdx.x];
    if (threadIdx.x == 1023) partials[blockIdx.x] = sh[1023];
}

__global__ __launch_bounds__(1024) void k_scan_partials(int* __restrict__ partials, int nb) {
    __shared__ int sh[1024];
    int v = (threadIdx.x < nb) ? partials[threadIdx.x] : 0;
    sh[threadIdx.x] = v;
    __syncthreads();
    for (int off = 1; off < 1024; off <<= 1) {
        int t = (threadIdx.x >= off) ? sh[threadIdx.x - off] : 0;
        __syncthreads();
        sh[threadIdx.x] += t;
        __syncthreads();
    }
    if (threadIdx.x < nb) partials[threadIdx.x] = sh[threadIdx.x] - v;
}

__global__ void k_scan_finalize(int* __restrict__ row_ptr, const int* __restrict__ partials,
                                int n) {
    int i = blockIdx.x * blockDim.x + threadIdx.x;
    if (i < n) {
        row_ptr[i + 1] += partials[i >> 10];
        if (i == 0) row_ptr[0] = 0;
    }
}

// ---------------- deterministic CSR scatter (no global atomics) ----------------
__global__ __launch_bounds__(256) void k_scatter_lds(const int* __restrict__ src,
                                                     const int* __restrict__ dst,
                                                     const unsigned int* __restrict__ pD,
                                                     const int* __restrict__ row_ptr,
                                                     int* __restrict__ ssrc, int E, int EPS) {
    __shared__ unsigned int cur[RANGE / 2];   // 32 KB
    const int r = blockIdx.x & 7;
    const int s = blockIdx.x >> 3;
    const unsigned int* pre = pD + ((size_t)r * NSLICE + s) * (RANGE / 2);
    for (int i = threadIdx.x; i < RANGE / 2; i += 256) cur[i] = pre[i];
    __syncthreads();
    const int e0 = s * EPS;
    const int e1 = min(E, e0 + EPS);
    int e = e0 + threadIdx.x * 4;
    for (; e + 3 < e1; e += 1024) {
        const int4 v = *(const int4*)&dst[e];
#pragma unroll
        for (int j = 0; j < 4; ++j) {
            const int d = (&v.x)[j];
            if ((d >> RANGE_BITS) == r) {
                const int local = d & (RANGE - 1);
                const int sh = (local & 1) << 4;
                const unsigned int old = atomicAdd(&cur[local >> 1], 1u << sh);
                const unsigned int off = (old >> sh) & 0xffffu;
                ssrc[row_ptr[d] + (int)off] = src[e + j];
            }
        }
    }
    for (; e < e1; ++e) {
        const int d = dst[e];
        if ((d >> RANGE_BITS) == r) {
            const int local = d & (RANGE - 1);
            const int sh = (local & 1) << 4;
            const unsigned int old = atomicAdd(&cur[local >> 1], 1u << sh);
            const unsigned int off = (old >> sh) & 0xffffu;
            ssrc[row_ptr[d] + (int)off] = src[e];
        }
    }
}

// ---------------- MFMA GEMM: out_w[N,128](bf16) = rowscale?(X @ W_w) ----------------
template <typename TIN, int NW, bool SCALE0>
__global__ __launch_bounds__(256) void gemm_mfma(const TIN* __restrict__ X,
                                                 const unsigned short* __restrict__ Wt0,
                                                 const unsigned short* __restrict__ Wt1,
                                                 const float* __restrict__ scale,
                                                 unsigned short* __restrict__ out0,
                                                 unsigned short* __restrict__ out1,
                                                 int N) {
    __shared__ unsigned short Ws[NW][128 * 128];   // 32 KB per weight (64 KB max)
    const int tid = threadIdx.x;
#pragma unroll
    for (int w = 0; w < NW; ++w) {
        const unsigned short* Wsrc = w ? Wt1 : Wt0;
        for (int i = tid; i < 2048; i += 256) {
            const int n = i >> 4, b = i & 15;
            const uint4 v = *(const uint4*)&Wsrc[(size_t)n * 128 + b * 8];
            *(uint4*)&Ws[w][n * 128 + ((b ^ (n & 15)) << 3)] = v;
        }
    }
    __syncthreads();

    const int lane = tid & 63;
    const int wave = tid >> 6;
    const int quad = lane >> 4;
    const int l16 = lane & 15;
    const int r_base = blockIdx.x * 64 + wave * 16;
    const int ra = min(r_base + l16, N - 1);          // A-operand row (clamped)

    f4v acc[NW][8];
#pragma unroll
    for (int w = 0; w < NW; ++w)
#pragma unroll
        for (int nn = 0; nn < 8; ++nn) acc[w][nn] = (f4v)0.f;

    const TIN* xp = X + (size_t)ra * 128 + quad * 8;

#pragma unroll
    for (int kt = 0; kt < 4; ++kt) {
        s8v af;
        if constexpr (sizeof(TIN) == 4) {
            const float4 lo = *(const float4*)(xp + kt * 32);
            const float4 hi = *(const float4*)(xp + kt * 32 + 4);
            af[0] = (short)f2bf(lo.x); af[1] = (short)f2bf(lo.y);
            af[2] = (short)f2bf(lo.z); af[3] = (short)f2bf(lo.w);
            af[4] = (short)f2bf(hi.x); af[5] = (short)f2bf(hi.y);
            af[6] = (short)f2bf(hi.z); af[7] = (short)f2bf(hi.w);
        } else {
            af = *(const s8v*)(xp + kt * 32);
        }
#pragma unroll
        for (int nn = 0; nn < 8; ++nn) {
            const int bofs = (nn * 16 + l16) * 128 + (((kt * 4 + quad) ^ l16) << 3);
#pragma unroll
            for (int w = 0; w < NW; ++w) {
                const s8v bf = *(const s8v*)&Ws[w][bofs];
                acc[w][nn] = mfma16(af, bf, acc[w][nn]);
            }
        }
    }

    // epilogue: C/D layout col = lane&15, row = quad*4 + reg
    const int rc = r_base + quad * 4;
    float sc[4];
    if constexpr (SCALE0) {
#pragma unroll
        for (int g = 0; g < 4; ++g) sc[g] = scale[min(rc + g, N - 1)];
    }
#pragma unroll
    for (int nn = 0; nn < 8; ++nn) {
        const int col = nn * 16 + l16;
#pragma unroll
        for (int g = 0; g < 4; ++g) {
            const int r = rc + g;
            if (r < N) {
                float v0 = acc[0][nn][g];
                if constexpr (SCALE0) v0 *= sc[g];
                out0[(size_t)r * 128 + col] = (unsigned short)f2bf(v0);
                if constexpr (NW == 2)
                    out1[(size_t)r * 128 + col] = (unsigned short)f2bf(acc[1][nn][g]);
            }
        }
    }
}

// ---------------- CSR aggregation (one wave per dst node) ----------------
// 16-lane group per edge, uint4 (16B) per lane: one load instruction gathers
// 4 edges' rows (1 KB). Two clamped unconditional loads per step (8 edges in
// flight); tail masked via fmaf. Cross-group shfl_xor(16/32) reduce at end.
template <int FINAL>
__global__ __launch_bounds__(256) void spmm_agg(const unsigned short* __restrict__ T,
                                                const int* __restrict__ row_ptr,
                                                const int* __restrict__ ssrc,
                                                const float* __restrict__ in_norm,
                                                const float* __restrict__ bias,
                                                unsigned short* __restrict__ Hout,
                                                const unsigned short* __restrict__ Res,
                                                const float* __restrict__ mlpW,
                                                const float* __restrict__ mlpB,
                                                float* __restrict__ out, int N) {
    const int lane = threadIdx.x & 63;
    const int grp = lane >> 4;        // edge group 0..3
    const int gl  = lane & 15;        // 16B column chunk within row
    const int d = blockIdx.x * 4 + (threadIdx.x >> 6);
    if (d >= N) return;

    const int start = row_ptr[d], end = row_ptr[d + 1];
    float acc[8];
#pragma unroll
    for (int j = 0; j < 8; ++j) acc[j] = 0.f;

    for (int base = start; base < end; base += 64) {
        const int cnt = min(64, end - base);
        const int sl = (lane < cnt) ? ssrc[base + lane] : 0;
        for (int i = 0; i < cnt; i += 8) {
            const int e0 = i + grp, e1 = i + 4 + grp;
            const int s0 = __shfl(sl, min(e0, cnt - 1));
            const int s1 = __shfl(sl, min(e1, cnt - 1));
            const uint4 w0 = *(const uint4*)&T[(size_t)s0 * 128 + gl * 8];
            const uint4 w1 = *(const uint4*)&T[(size_t)s1 * 128 + gl * 8];
            const float m0 = (e0 < cnt) ? 1.f : 0.f;
            const float m1 = (e1 < cnt) ? 1.f : 0.f;
            acc[0] = fmaf(m0, bflo(w0.x), acc[0]); acc[1] = fmaf(m0, bfhi(w0.x), acc[1]);
            acc[2] = fmaf(m0, bflo(w0.y), acc[2]); acc[3] = fmaf(m0, bfhi(w0.y), acc[3]);
            acc[4] = fmaf(m0, bflo(w0.z), acc[4]); acc[5] = fmaf(m0, bfhi(w0.z), acc[5]);
            acc[6] = fmaf(m0, bflo(w0.w), acc[6]); acc[7] = fmaf(m0, bfhi(w0.w), acc[7]);
            acc[0] = fmaf(m1, bflo(w1.x), acc[0]); acc[1] = fmaf(m1, bfhi(w1.x), acc[1]);
            acc[2] = fmaf(m1, bflo(w1.y), acc[2]); acc[3] = fmaf(m1, bfhi(w1.y), acc[3]);
            acc[4] = fmaf(m1, bflo(w1.z), acc[4]); acc[5] = fmaf(m1, bfhi(w1.z), acc[5]);
            acc[6] = fmaf(m1, bflo(w1.w), acc[6]); acc[7] = fmaf(m1, bfhi(w1.w), acc[7]);
        }
    }

    // sum the 4 edge-groups (same columns, different edges)
#pragma unroll
    for (int j = 0; j < 8; ++j) {
        acc[j] += __shfl_xor(acc[j], 16);
        acc[j] += __shfl_xor(acc[j], 32);
    }

    const float inr = in_norm[d];
    const float4 bb0 = *(const float4*)&bias[gl * 8];
    const float4 bb1 = *(const float4*)&bias[gl * 8 + 4];
    float v[8];
    v[0] = acc[0] * inr + bb0.x; v[1] = acc[1] * inr + bb0.y;
    v[2] = acc[2] * inr + bb0.z; v[3] = acc[3] * inr + bb0.w;
    v[4] = acc[4] * inr + bb1.x; v[5] = acc[5] * inr + bb1.y;
    v[6] = acc[6] * inr + bb1.z; v[7] = acc[7] * inr + bb1.w;

    if constexpr (FINAL == 0) {
#pragma unroll
        for (int j = 0; j < 8; ++j) v[j] = fmaxf(v[j], 0.f);
        if (grp == 0) {
            uint4 o;
            o.x = packbf(v[0], v[1]); o.y = packbf(v[2], v[3]);
            o.z = packbf(v[4], v[5]); o.w = packbf(v[6], v[7]);
            *(uint4*)&Hout[(size_t)d * 128 + gl * 8] = o;
        }
    } else {
        const uint4 rw = *(const uint4*)&Res[(size_t)d * 128 + gl * 8];
        v[0] += bflo(rw.x); v[1] += bfhi(rw.x);
        v[2] += bflo(rw.y); v[3] += bfhi(rw.y);
        v[4] += bflo(rw.z); v[5] += bfhi(rw.z);
        v[6] += bflo(rw.w); v[7] += bfhi(rw.w);
        // mlpW rows gl*8..gl*8+7, 2 floats each = 4 float4
        const float4* mwp = (const float4*)&mlpW[gl * 16];
        float p0 = 0.f, p1 = 0.f;
#pragma unroll
        for (int q = 0; q < 4; ++q) {
            const float4 mw = mwp[q];
            p0 = fmaf(v[2 * q], mw.x, p0);     p1 = fmaf(v[2 * q], mw.y, p1);
            p0 = fmaf(v[2 * q + 1], mw.z, p0); p1 = fmaf(v[2 * q + 1], mw.w, p1);
        }
#pragma unroll
        for (int off = 8; off > 0; off >>= 1) {
            p0 += __shfl_xor(p0, off);
            p1 += __shfl_xor(p1, off);
        }
        if (lane == 0) {
            out[(size_t)d * 2 + 0] = p0 + mlpB[0];
            out[(size_t)d * 2 + 1] = p1 + mlpB[1];
        }
    }
}

// ---------------- launch ----------------
extern "C" void kernel_launch(void* const* d_in, const int* in_sizes, int n_in,
                              void* d_out, int out_size, void* d_ws, size_t ws_size,
                              hipStream_t stream) {
    const float* x     = (const float*)d_in[0];
    const int*   src   = (const int*)d_in[1];
    const int*   dst   = (const int*)d_in[2];
    const float* W1    = (const float*)d_in[3];
    const float* b1    = (const float*)d_in[4];
    const float* W2    = (const float*)d_in[5];
    const float* b2    = (const float*)d_in[6];
    const float* res_W = (const float*)d_in[7];
    const float* mlp_W = (const float*)d_in[8];
    const float* mlp_b = (const float*)d_in[9];
    float* out = (float*)d_out;

    const int N = in_sizes[0] / 128;
    const int E = in_sizes[1];
    const int EPS = (E + NSLICE - 1) / NSLICE;

    // workspace layout. partialS aliases A, partialD aliases C: both are dead
    // before the first GEMM writes A/C (deg_reduce & scatter consume them earlier).
    char* p = (char*)d_ws;
    unsigned short* A = (unsigned short*)p;  p += (size_t)N * 128 * 2;   // t1 / t2
    unsigned short* B = (unsigned short*)p;  p += (size_t)N * 128 * 2;   // h1
    unsigned short* C = (unsigned short*)p;  p += (size_t)N * 128 * 2;   // res (aliases partialD)
    unsigned short* Wt = (unsigned short*)p; p += (size_t)3 * 16384 * 2; // Wt1|Wt2|Rt bf16
    float* out_norm = (float*)p;             p += (size_t)N * 4;
    float* in_norm  = (float*)p;             p += (size_t)N * 4;
    int* in_deg     = (int*)p;               p += (size_t)N * 4;
    int* row_ptr    = (int*)p;               p += (size_t)(N + 1) * 4;
    int* scanpart   = (int*)p;               p += (size_t)1024 * 4;
    int* ssrc       = (int*)p;               p += (size_t)E * 4;
    unsigned int* partialS = (unsigned int*)A;
    unsigned int* partialD = (unsigned int*)C;

    const int gN = (N + 255) / 256;
    const int nb = (N + 1023) / 1024;
    const int gGemm = (N + 63) / 64;
    const int gSpmm = (N + 3) / 4;

    // 0. weights -> transposed bf16
    k_prep_w<<<dim3(3, 4), 256, 0, stream>>>(W1, W2, res_W, Wt);

    // 1. degrees + norms + slice prefixes (no global atomics)
    k_hist_lds<<<dim3(NR_PAD * NSLICE, 2), 256, 0, stream>>>(src, dst, partialS, partialD, E, EPS);
    k_deg_reduce<<<dim3(NR_PAD * (RANGE / 2) / 256, 2), 256, 0, stream>>>(partialS, partialD,
                                                                          out_norm, in_norm, in_deg, N);

    // 2. row_ptr scan + deterministic CSR scatter
    k_scan_block<<<nb, 1024, 0, stream>>>(in_deg, row_ptr, scanpart, N);
    k_scan_partials<<<1, 1024, 0, stream>>>(scanpart, nb);
    k_scan_finalize<<<gN, 256, 0, stream>>>(row_ptr, scanpart, N);
    k_scatter_lds<<<NR_PAD * NSLICE, 256, 0, stream>>>(src, dst, partialD, row_ptr, ssrc, E, EPS);

    // 3. fused gemm1+gemm3: A = rowscale(x@W1, out_norm), C = x@res_W
    gemm_mfma<float, 2, true><<<gGemm, 256, 0, stream>>>(x, Wt, Wt + 2 * 16384, out_norm, A, C, N);

    // 4. layer-1 aggregation: B = relu(agg(A)*in_norm + b1)
    spmm_agg<0><<<gSpmm, 256, 0, stream>>>(A, row_ptr, ssrc, in_norm, b1, B,
                                           (const unsigned short*)nullptr, nullptr, nullptr,
                                           nullptr, N);

    // 5. gemm2: A = rowscale(B@W2, out_norm)
    gemm_mfma<unsigned short, 1, true><<<gGemm, 256, 0, stream>>>(B, Wt + 16384, nullptr,
                                                                  out_norm, A, nullptr, N);

    // 6. final aggregation + residual + MLP head -> out
    spmm_agg<1><<<gSpmm, 256, 0, stream>>>(A, row_ptr, ssrc, in_norm, b2, nullptr,
                                           C, mlp_W, mlp_b, out, N);

    (void)n_in; (void)out_size; (void)ws_size;
}